// Round 1
// baseline (1812.834 us; speedup 1.0000x reference)
//
#include <hip/hip_runtime.h>
#include <math.h>

#define DEVI __device__ __forceinline__

namespace {

constexpr int N_  = 2048;
constexpr int E_  = 32768;
constexpr int E2_ = 65536;
constexpr int M_  = 64000;   // 8 * 20^3

DEVI float sigm(float x)  { return 1.0f/(1.0f+expf(-x)); }
DEVI float geluf(float x) {
  float t = tanhf(0.7978845608028654f*(x + 0.044715f*x*x*x));
  return 0.5f*x*(1.0f+t);
}

// ---------------- utility ----------------
__global__ void zero_k(float* __restrict__ p, int n){
  int i = blockIdx.x*256 + threadIdx.x;
  if (i < n) p[i] = 0.0f;
}

__global__ void meshpos_k(const float* __restrict__ cell, float* __restrict__ mp){
  int m = blockIdx.x*256 + threadIdx.x;
  if (m >= M_) return;
  int b = m/8000, r = m%8000;
  float fx = (float)(r/400)    * 0.05f;
  float fy = (float)((r/20)%20)* 0.05f;
  float fz = (float)(r%20)     * 0.05f;
  const float* c = cell + b*9;
  mp[(size_t)m*3+0] = fx*c[0] + fy*c[3] + fz*c[6];
  mp[(size_t)m*3+1] = fx*c[1] + fy*c[4] + fz*c[7];
  mp[(size_t)m*3+2] = fx*c[2] + fy*c[5] + fz*c[8];
}

// edge geometry: ev = P[pi[e]] - Q[qi[e]]; writes sh (9) and gauss emb (64)
__global__ void edge_geom_k(const float* __restrict__ Ppos, const int* __restrict__ pi,
                            const float* __restrict__ Qpos, const int* __restrict__ qi,
                            float* __restrict__ sh, float* __restrict__ emb, int nE){
  int e = blockIdx.x;
  if (e >= nE) return;
  int lane = threadIdx.x;  // 64
  int a = pi[e], b = qi[e];
  float ex = Ppos[(size_t)a*3+0] - Qpos[(size_t)b*3+0];
  float ey = Ppos[(size_t)a*3+1] - Qpos[(size_t)b*3+1];
  float ez = Ppos[(size_t)a*3+2] - Qpos[(size_t)b*3+2];
  float el = sqrtf(ex*ex+ey*ey+ez*ez) + 1e-8f;
  const float step = 5.0f/63.0f;
  float val = lane * step;               // linspace(0,5,64)
  float d = (el - val)/step;
  emb[(size_t)e*64 + lane] = expf(-d*d) * (8.0f/1.12f);
  if (lane == 0) {
    float x = ex/el, y = ey/el, z = ez/el;
    float* s = sh + (size_t)e*9;
    s[0] = 0.28209479177387814f;
    s[1] = 0.4886025119029199f*y;
    s[2] = 0.4886025119029199f*z;
    s[3] = 0.4886025119029199f*x;
    s[4] = 1.0925484305920792f*x*y;
    s[5] = 1.0925484305920792f*y*z;
    s[6] = 0.31539156525252005f*(3.0f*z*z-1.0f);
    s[7] = 1.0925484305920792f*x*z;
    s[8] = 0.5462742152960396f*(x*x-y*y);
  }
}

__global__ void gather_emb_k(const float* __restrict__ emb, const int* __restrict__ an,
                             float* __restrict__ x16){
  int idx = blockIdx.x*256 + threadIdx.x;
  if (idx >= N_*16) return;
  int n = idx >> 4, f = idx & 15;
  x16[idx] = emb[(size_t)an[n]*16 + f];
}

// ---------------- generic tiled GEMM: C = act(A@B) ----------------
// A: Mr x K row-major, B: K x Nc row-major.  ACT: 0 none, 1 silu
#define BM 64
#define BN 64
#define BK 16
template<int ACT>
__global__ __launch_bounds__(256) void gemm_k(const float* __restrict__ A, const float* __restrict__ B,
                      float* __restrict__ C, int Mr, int K, int Nc){
  __shared__ float As[BK][BM+4];
  __shared__ float Bs[BK][BN+4];
  int tid = threadIdx.x;
  int row0 = blockIdx.y*BM, col0 = blockIdx.x*BN;
  int tx = tid & 15, ty = tid >> 4;
  float acc[4][4] = {};
  for (int k0 = 0; k0 < K; k0 += BK) {
    { int kk = tid & 15; int mloc = tid >> 4;
      int gk = k0 + kk;
      for (int p = 0; p < 4; ++p) {
        int m = mloc + p*16; int gm = row0 + m;
        As[kk][m] = (gm < Mr && gk < K) ? A[(size_t)gm*K + gk] : 0.0f;
      } }
    { int nn = tid & 63; int kl = tid >> 6;
      for (int p = 0; p < 4; ++p) {
        int kk = kl + p*4; int gk = k0 + kk; int gn = col0 + nn;
        Bs[kk][nn] = (gk < K && gn < Nc) ? B[(size_t)gk*Nc + gn] : 0.0f;
      } }
    __syncthreads();
    #pragma unroll
    for (int kk = 0; kk < BK; ++kk) {
      float a[4], b[4];
      #pragma unroll
      for (int i=0;i<4;++i) a[i] = As[kk][ty*4+i];
      #pragma unroll
      for (int j=0;j<4;++j) b[j] = Bs[kk][tx*4+j];
      #pragma unroll
      for (int i=0;i<4;++i)
        #pragma unroll
        for (int j=0;j<4;++j) acc[i][j] += a[i]*b[j];
    }
    __syncthreads();
  }
  for (int i=0;i<4;++i) {
    int gm = row0 + ty*4+i; if (gm >= Mr) continue;
    for (int j=0;j<4;++j) {
      int gn = col0 + tx*4+j; if (gn >= Nc) continue;
      float v = acc[i][j];
      if (ACT==1) v = v/(1.0f+expf(-v));
      C[(size_t)gm*Nc + gn] = v;
    }
  }
}

// expand GEMM: C = (x[src] outer sh) @ W ; A[e, f*9+s] = X[src[e]*F+f]*sh[e,s]
template<int F>
__global__ __launch_bounds__(256) void egemm_k(const float* __restrict__ X, const int* __restrict__ src,
                      const float* __restrict__ SH, const float* __restrict__ B,
                      float* __restrict__ C, int Mr, int Nc){
  constexpr int K = F*9;
  __shared__ float As[BK][BM+4];
  __shared__ float Bs[BK][BN+4];
  __shared__ int   srcIdx[BM];
  __shared__ float shs[BM][10];
  int tid = threadIdx.x;
  int row0 = blockIdx.y*BM, col0 = blockIdx.x*BN;
  if (tid < BM) srcIdx[tid] = (row0+tid < Mr) ? src[row0+tid] : 0;
  for (int t = tid; t < BM*9; t += 256) {
    int m = t/9, s = t - m*9;
    shs[m][s] = (row0+m < Mr) ? SH[(size_t)(row0+m)*9 + s] : 0.0f;
  }
  __syncthreads();
  int tx = tid & 15, ty = tid >> 4;
  float acc[4][4] = {};
  for (int k0 = 0; k0 < K; k0 += BK) {
    { int kk = tid & 15; int mloc = tid >> 4;
      int gk = k0 + kk; int f = gk/9, s = gk - f*9;
      for (int p = 0; p < 4; ++p) {
        int m = mloc + p*16; int gm = row0 + m;
        As[kk][m] = (gm < Mr) ? X[(size_t)srcIdx[m]*F + f] * shs[m][s] : 0.0f;
      } }
    { int nn = tid & 63; int kl = tid >> 6;
      for (int p = 0; p < 4; ++p) {
        int kk = kl + p*4; int gk = k0 + kk; int gn = col0 + nn;
        Bs[kk][nn] = (gn < Nc) ? B[(size_t)gk*Nc + gn] : 0.0f;
      } }
    __syncthreads();
    #pragma unroll
    for (int kk = 0; kk < BK; ++kk) {
      float a[4], b[4];
      #pragma unroll
      for (int i=0;i<4;++i) a[i] = As[kk][ty*4+i];
      #pragma unroll
      for (int j=0;j<4;++j) b[j] = Bs[kk][tx*4+j];
      #pragma unroll
      for (int i=0;i<4;++i)
        #pragma unroll
        for (int j=0;j<4;++j) acc[i][j] += a[i]*b[j];
    }
    __syncthreads();
  }
  for (int i=0;i<4;++i) {
    int gm = row0 + ty*4+i; if (gm >= Mr) continue;
    for (int j=0;j<4;++j) {
      int gn = col0 + tx*4+j; if (gn >= Nc) continue;
      C[(size_t)gm*Nc + gn] = acc[i][j];
    }
  }
}

// ---------------- GCN pieces ----------------
__global__ void normact_k(const float* __restrict__ x, float* __restrict__ y){
  int idx = blockIdx.x*256 + threadIdx.x;
  if (idx >= N_*16) return;
  int n = idx >> 4, r = idx & 15;
  const float* xr = x + (size_t)n*144;
  float* yr = y + (size_t)n*144;
  float s = xr[r];
  yr[r] = s * sigm(fabsf(s));
  float v0 = xr[16+r*3], v1 = xr[16+r*3+1], v2 = xr[16+r*3+2];
  float gv = sigm(sqrtf(v0*v0+v1*v1+v2*v2));
  yr[16+r*3]=v0*gv; yr[16+r*3+1]=v1*gv; yr[16+r*3+2]=v2*gv;
  float t0=xr[64+r*5],t1=xr[64+r*5+1],t2=xr[64+r*5+2],t3=xr[64+r*5+3],t4=xr[64+r*5+4];
  float gt = sigm(sqrtf(t0*t0+t1*t1+t2*t2+t3*t3+t4*t4));
  yr[64+r*5]=t0*gt; yr[64+r*5+1]=t1*gt; yr[64+r*5+2]=t2*gt; yr[64+r*5+3]=t3*gt; yr[64+r*5+4]=t4*gt;
}

// out[n,o] = sum_f xin[n,f]*Wsc[f,o]  (self-connection init before scatter)
__global__ void wscinit_k(const float* __restrict__ xin, const float* __restrict__ Wsc,
                          float* __restrict__ out, int nRows, int Kf, int Of){
  int idx = blockIdx.x*256 + threadIdx.x;
  if (idx >= nRows*Of) return;
  int n = idx / Of, o = idx - n*Of;
  float acc = 0.0f;
  for (int f = 0; f < Kf; ++f) acc += xin[(size_t)n*Kf+f]*Wsc[(size_t)f*Of+o];
  out[idx] = acc;
}

__global__ void scatter_k(const float* __restrict__ msgW, const float* __restrict__ rout,
                          const int* __restrict__ dst, float* __restrict__ out, int nE, int O){
  int idx = blockIdx.x*256 + threadIdx.x;
  if (idx >= nE*O) return;
  int e = idx / O, o = idx - e*O;
  atomicAdd(&out[(size_t)dst[e]*O + o], msgW[idx]*rout[idx]);
}

__global__ void sigabs_k(float* __restrict__ x, int n){
  int i = blockIdx.x*256 + threadIdx.x;
  if (i < n) { float v = x[i]; x[i] = v * sigm(fabsf(v)); }
}

// ---------------- FNO ----------------
__global__ void fc0_k(const float* __restrict__ mf, const float* __restrict__ Wt,
                      const float* __restrict__ bb, float* __restrict__ h){
  int idx = blockIdx.x*256 + threadIdx.x;
  if (idx >= M_*16) return;
  int m = idx >> 4, o = idx & 15;
  int r = m % 8000;
  float fx = (float)(r/400)*0.05f, fy = (float)((r/20)%20)*0.05f, fz = (float)(r%20)*0.05f;
  const float* mfr = mf + (size_t)m*32;
  float acc = bb[o];
  #pragma unroll
  for (int j=0;j<32;++j) acc += mfr[j]*Wt[j*16+o];
  acc += fx*Wt[32*16+o] + fy*Wt[33*16+o] + fz*Wt[34*16+o];
  h[idx] = acc;
}

// real->complex DFT along z, keep kz=0..9. out[b][x][y][kz][i]
__global__ void zfwd_k(const float* __restrict__ h, float2* __restrict__ out){
  __shared__ float2 tw[20];
  if (threadIdx.x < 20) { float a = -6.283185307179586f*threadIdx.x/20.0f; tw[threadIdx.x] = make_float2(cosf(a), sinf(a)); }
  __syncthreads();
  int idx = blockIdx.x*256 + threadIdx.x;
  if (idx >= 512000) return;
  int i = idx & 15;
  int kz = (idx >> 4) % 10;
  int bxy = idx / 160;
  const float* hp = h + (size_t)bxy*320 + i;
  float sr=0.0f, si=0.0f; int j=0;
  for (int z=0; z<20; ++z) {
    float v = hp[z*16];
    float2 t = tw[j];
    sr += v*t.x; si += v*t.y;
    j += kz; if (j >= 20) j -= 20;
  }
  out[idx] = make_float2(sr, si);
}

// complex DFT along an axis of length 20 (inner stride innerSz), sign=-1 fwd, +1 inv
__global__ void cdft_k(const float2* __restrict__ in, float2* __restrict__ out,
                       int innerSz, int total, float sign){
  __shared__ float2 tw[20];
  if (threadIdx.x < 20) { float a = sign*6.283185307179586f*threadIdx.x/20.0f; tw[threadIdx.x] = make_float2(cosf(a), sinf(a)); }
  __syncthreads();
  int idx = blockIdx.x*256 + threadIdx.x;
  if (idx >= total) return;
  int inner = idx % innerSz;
  int ko = (idx / innerSz) % 20;
  int outer = idx / (innerSz*20);
  const float2* ip = in + (size_t)outer*20*innerSz + inner;
  float sr=0.0f, si=0.0f; int j=0;
  for (int t=0;t<20;++t) {
    float2 v = ip[(size_t)t*innerSz];
    float2 w = tw[j];
    sr += v.x*w.x - v.y*w.y;
    si += v.x*w.y + v.y*w.x;
    j += ko; if (j >= 20) j -= 20;
  }
  out[idx] = make_float2(sr, si);
}

// channel mix with corner weights. in/out [b][kx][ky][kz][ch]
__global__ void mix_k(const float2* __restrict__ in, float2* __restrict__ out,
                      const float* __restrict__ wr, const float* __restrict__ wi){
  int idx = blockIdx.x*256 + threadIdx.x;
  if (idx >= 512000) return;
  int o = idx & 15;
  int kz = (idx >> 4) % 10;
  int t = idx / 160;                  // (b*20+kx)*20+ky
  int ky = t % 20, kx = (t/20) % 20;
  int c = (kx>=10 ? 1 : 0) + (ky>=10 ? 2 : 0);
  int xx = kx % 10, yy = ky % 10;
  size_t wbase = ((size_t)(c*16)*16 + o)*1000 + xx*100 + yy*10 + kz;
  size_t ibase = (size_t)t*160 + kz*16;
  float sr=0.0f, si=0.0f;
  #pragma unroll
  for (int i=0;i<16;++i) {
    float2 a = in[ibase + i];
    float wrv = wr[wbase + (size_t)i*16000];
    float wiv = wi[wbase + (size_t)i*16000];
    sr += a.x*wrv - a.y*wiv;
    si += a.x*wiv + a.y*wrv;
  }
  out[idx] = make_float2(sr, si);
}

// inverse real transform along z (numpy irfft semantics: Im(bin0) ignored, Nyquist zero)
__global__ void zinv_k(const float2* __restrict__ in, float* __restrict__ spec){
  __shared__ float2 tw[20];
  if (threadIdx.x < 20) { float a = 6.283185307179586f*threadIdx.x/20.0f; tw[threadIdx.x] = make_float2(cosf(a), sinf(a)); }
  __syncthreads();
  int idx = blockIdx.x*256 + threadIdx.x;
  if (idx >= M_*16) return;
  int o = idx & 15;
  int z = (idx >> 4) % 20;
  int bxy = idx / 320;
  const float2* ip = in + (size_t)bxy*160 + o;
  float acc = 0.0f; int j=0;
  for (int kz=0;kz<10;++kz) {
    float2 v = ip[kz*16];
    float2 w = tw[j];
    float re = v.x*w.x - v.y*w.y;
    acc += (kz==0) ? re : 2.0f*re;
    j += z; if (j >= 20) j -= 20;
  }
  spec[idx] = acc * (1.0f/8000.0f);
}

__global__ void pwgelu_k(const float* __restrict__ spec, const float* __restrict__ h,
                         const float* __restrict__ pw, float* __restrict__ out){
  int idx = blockIdx.x*256 + threadIdx.x;
  if (idx >= M_*16) return;
  int m = idx >> 4, o = idx & 15;
  const float* hr = h + (size_t)m*16;
  float acc = spec[idx];
  #pragma unroll
  for (int i=0;i<16;++i) acc += hr[i]*pw[i*16+o];
  out[idx] = geluf(acc);
}

__global__ void ff1g_k(const float* __restrict__ h, const float* __restrict__ Wt, float* __restrict__ out){
  int idx = blockIdx.x*256 + threadIdx.x;
  if (idx >= M_*64) return;
  int m = idx >> 6, j = idx & 63;
  const float* hr = h + (size_t)m*16;
  float acc = 0.0f;
  #pragma unroll
  for (int i=0;i<16;++i) acc += hr[i]*Wt[i*64+j];
  out[idx] = geluf(acc);
}

__global__ void ffout_k(const float* __restrict__ hB, const float* __restrict__ t,
                        const float* __restrict__ Wt, float* __restrict__ h){
  int idx = blockIdx.x*256 + threadIdx.x;
  if (idx >= M_*16) return;
  int m = idx >> 4, o = idx & 15;
  const float* tr = t + (size_t)m*64;
  float acc = hB[idx];
  #pragma unroll
  for (int j=0;j<64;++j) acc += tr[j]*Wt[j*16+o];
  h[idx] = acc;
}

__global__ void fc1g_k(const float* __restrict__ h, const float* __restrict__ Wt, float* __restrict__ out){
  int idx = blockIdx.x*256 + threadIdx.x;
  if (idx >= M_*128) return;
  int m = idx >> 7, j = idx & 127;
  const float* hr = h + (size_t)m*16;
  float acc = 0.0f;
  #pragma unroll
  for (int i=0;i<16;++i) acc += hr[i]*Wt[i*128+j];
  out[idx] = geluf(acc);
}

__global__ void fc2_k(const float* __restrict__ t, const float* __restrict__ Wt, float* __restrict__ out){
  int idx = blockIdx.x*256 + threadIdx.x;
  if (idx >= M_*16) return;
  int m = idx >> 4, o = idx & 15;
  const float* tr = t + (size_t)m*128;
  float acc = 0.0f;
  #pragma unroll
  for (int j=0;j<128;++j) acc += tr[j]*Wt[j*16+o];
  out[idx] = acc;
}

// ---------------- m2a + final ----------------
__global__ void dot128_k(const float* __restrict__ A, const float* __restrict__ w,
                         float* __restrict__ out, int rows){
  int e = blockIdx.x*256 + threadIdx.x;
  if (e >= rows) return;
  const float* ar = A + (size_t)e*128;
  float acc = 0.0f;
  #pragma unroll
  for (int k=0;k<128;++k) acc += ar[k]*w[k];
  out[e] = acc;
}

__global__ void m2a_k(const float* __restrict__ mf2, const int* __restrict__ mdst,
                      const int* __restrict__ asrc, const float* __restrict__ sh2,
                      const float* __restrict__ Wt, const float* __restrict__ rvec,
                      float* __restrict__ af){
  int e = blockIdx.x*256 + threadIdx.x;
  if (e >= E2_) return;
  const float* xr = mf2 + (size_t)mdst[e]*16;
  const float* sr = sh2 + (size_t)e*9;
  float sh[9];
  #pragma unroll
  for (int s=0;s<9;++s) sh[s] = sr[s];
  float acc = 0.0f;
  #pragma unroll
  for (int f=0;f<16;++f) {
    float xv = xr[f];
    float dot = 0.0f;
    #pragma unroll
    for (int s=0;s<9;++s) dot += sh[s]*Wt[f*9+s];
    acc += xv*dot;
  }
  atomicAdd(&af[asrc[e]], acc*rvec[e]);
}

__global__ void bsum_k(const float* __restrict__ af, const int* __restrict__ batch,
                       float* __restrict__ out){
  int n = blockIdx.x*256 + threadIdx.x;
  if (n >= N_) return;
  atomicAdd(&out[batch[n]], af[n]);
}

} // namespace

extern "C" void kernel_launch(void* const* d_in, const int* in_sizes, int n_in,
                              void* d_out, int out_size, void* d_ws, size_t ws_size,
                              hipStream_t stream) {
  (void)in_sizes; (void)n_in; (void)out_size; (void)ws_size;
  const float* pos   = (const float*)d_in[0];
  const float* cell  = (const float*)d_in[1];
  const int*   an    = (const int*)d_in[2];
  const int*   batch = (const int*)d_in[3];
  const int*   esrc  = (const int*)d_in[4];
  const int*   edst  = (const int*)d_in[5];
  const int*   asrc  = (const int*)d_in[6];
  const int*   mdst  = (const int*)d_in[7];
  const float* emb   = (const float*)d_in[8];
  const float* g0_W  = (const float*)d_in[9];
  const float* g0_Wsc= (const float*)d_in[10];
  const float* g0_m1 = (const float*)d_in[11];
  const float* g0_m2 = (const float*)d_in[12];
  const float* g0_m3 = (const float*)d_in[13];
  const float* g12_W = (const float*)d_in[14];
  const float* g12_Wsc=(const float*)d_in[15];
  const float* g12_m1= (const float*)d_in[16];
  const float* g12_m2= (const float*)d_in[17];
  const float* g12_m3= (const float*)d_in[18];
  const float* a2m_W = (const float*)d_in[19];
  const float* a2m_m1= (const float*)d_in[20];
  const float* a2m_m2= (const float*)d_in[21];
  const float* a2m_m3= (const float*)d_in[22];
  const float* m2a_W = (const float*)d_in[23];
  const float* m2a_m1= (const float*)d_in[24];
  const float* m2a_m2= (const float*)d_in[25];
  const float* m2a_m3= (const float*)d_in[26];
  const float* fc0_W = (const float*)d_in[27];
  const float* fc0_b = (const float*)d_in[28];
  const float* sw_r  = (const float*)d_in[29];
  const float* sw_i  = (const float*)d_in[30];
  const float* pw    = (const float*)d_in[31];
  const float* ff1   = (const float*)d_in[32];
  const float* ff2   = (const float*)d_in[33];
  const float* fc1   = (const float*)d_in[34];
  const float* fc2   = (const float*)d_in[35];
  float* out = (float*)d_out;

  float* Wp = (float*)d_ws;
  size_t off = 0;
  auto alloc = [&](size_t n){ float* p = Wp + off; off += n; return p; };
  float* meshpos = alloc((size_t)M_*3);
  float* she   = alloc((size_t)E_*9);
  float* embe  = alloc((size_t)E_*64);
  float* sh2   = alloc((size_t)E2_*9);
  float* emb2  = alloc((size_t)E2_*64);
  float* x16   = alloc((size_t)N_*16);
  float* xatom = alloc((size_t)N_*144);
  float* xact  = alloc((size_t)N_*144);
  float* rh1   = alloc((size_t)E2_*128);
  float* rh2   = alloc((size_t)E2_*128);
  float* rout  = alloc((size_t)E_*144);
  float* msgW  = alloc((size_t)E_*144);
  float* mf    = alloc((size_t)M_*32);
  float* hbuf  = alloc((size_t)M_*16);
  float* htmp  = alloc((size_t)M_*16);
  float* htmp2 = alloc((size_t)M_*16);
  float2* cA   = (float2*)alloc(1024000);
  float2* cB   = (float2*)alloc(1024000);
  float* af    = alloc((size_t)N_);

  auto g1 = [](int n){ return dim3((unsigned)((n+255)/256)); };
  auto gg = [](int Mr, int Nc){ return dim3((unsigned)((Nc+63)/64), (unsigned)((Mr+63)/64)); };

  // zero accumulators
  zero_k<<<g1(8), 256, 0, stream>>>(out, 8);
  zero_k<<<g1(N_), 256, 0, stream>>>(af, N_);
  zero_k<<<g1(M_*32), 256, 0, stream>>>(mf, M_*32);

  // geometry
  meshpos_k<<<g1(M_), 256, 0, stream>>>(cell, meshpos);
  edge_geom_k<<<E_, 64, 0, stream>>>(pos, esrc, pos, edst, she, embe, E_);
  edge_geom_k<<<E2_, 64, 0, stream>>>(meshpos, mdst, pos, asrc, sh2, emb2, E2_);
  gather_emb_k<<<g1(N_*16), 256, 0, stream>>>(emb, an, x16);

  // ---- g0 ----
  gemm_k<1><<<gg(E_,128), 256, 0, stream>>>(embe, g0_m1, rh1, E_, 64, 128);
  gemm_k<1><<<gg(E_,128), 256, 0, stream>>>(rh1, g0_m2, rh2, E_, 128, 128);
  gemm_k<0><<<gg(E_,144), 256, 0, stream>>>(rh2, g0_m3, rout, E_, 128, 144);
  egemm_k<16><<<gg(E_,144), 256, 0, stream>>>(x16, esrc, she, g0_W, msgW, E_, 144);
  wscinit_k<<<g1(N_*144), 256, 0, stream>>>(x16, g0_Wsc, xatom, N_, 16, 144);
  scatter_k<<<g1(E_*144), 256, 0, stream>>>(msgW, rout, edst, xatom, E_, 144);

  // ---- g12 x2 ----
  for (int i = 0; i < 2; ++i) {
    normact_k<<<g1(N_*16), 256, 0, stream>>>(xatom, xact);
    gemm_k<1><<<gg(E_,128), 256, 0, stream>>>(embe, g12_m1 + (size_t)i*64*128, rh1, E_, 64, 128);
    gemm_k<1><<<gg(E_,128), 256, 0, stream>>>(rh1, g12_m2 + (size_t)i*128*128, rh2, E_, 128, 128);
    gemm_k<0><<<gg(E_,144), 256, 0, stream>>>(rh2, g12_m3 + (size_t)i*128*144, rout, E_, 128, 144);
    egemm_k<144><<<gg(E_,144), 256, 0, stream>>>(xact, esrc, she, g12_W + (size_t)i*1296*144, msgW, E_, 144);
    wscinit_k<<<g1(N_*144), 256, 0, stream>>>(xact, g12_Wsc + (size_t)i*144*144, xatom, N_, 144, 144);
    scatter_k<<<g1(E_*144), 256, 0, stream>>>(msgW, rout, edst, xatom, E_, 144);
  }

  // ---- a2m ----
  gemm_k<1><<<gg(E2_,128), 256, 0, stream>>>(emb2, a2m_m1, rh1, E2_, 64, 128);
  gemm_k<1><<<gg(E2_,128), 256, 0, stream>>>(rh1, a2m_m2, rh2, E2_, 128, 128);
  gemm_k<0><<<gg(E2_,32), 256, 0, stream>>>(rh2, a2m_m3, rout, E2_, 128, 32);
  egemm_k<144><<<gg(E2_,32), 256, 0, stream>>>(xatom, asrc, sh2, a2m_W, msgW, E2_, 32);
  scatter_k<<<g1(E2_*32), 256, 0, stream>>>(msgW, rout, mdst, mf, E2_, 32);
  sigabs_k<<<g1(M_*32), 256, 0, stream>>>(mf, M_*32);

  // ---- FNO ----
  fc0_k<<<g1(M_*16), 256, 0, stream>>>(mf, fc0_W, fc0_b, hbuf);
  for (int l = 0; l < 3; ++l) {
    zfwd_k<<<g1(512000), 256, 0, stream>>>(hbuf, cA);
    cdft_k<<<g1(512000), 256, 0, stream>>>(cA, cB, 160, 512000, -1.0f);  // y fwd
    cdft_k<<<g1(512000), 256, 0, stream>>>(cB, cA, 3200, 512000, -1.0f); // x fwd
    mix_k<<<g1(512000), 256, 0, stream>>>(cA, cB, sw_r + (size_t)l*1024000, sw_i + (size_t)l*1024000);
    cdft_k<<<g1(512000), 256, 0, stream>>>(cB, cA, 3200, 512000, 1.0f);  // x inv
    cdft_k<<<g1(512000), 256, 0, stream>>>(cA, cB, 160, 512000, 1.0f);   // y inv
    zinv_k<<<g1(M_*16), 256, 0, stream>>>(cB, htmp);
    pwgelu_k<<<g1(M_*16), 256, 0, stream>>>(htmp, hbuf, pw + (size_t)l*256, htmp2);
    ff1g_k<<<g1(M_*64), 256, 0, stream>>>(htmp2, ff1 + (size_t)l*1024, rh1);
    ffout_k<<<g1(M_*16), 256, 0, stream>>>(htmp2, rh1, ff2 + (size_t)l*1024, hbuf);
  }
  fc1g_k<<<g1(M_*128), 256, 0, stream>>>(hbuf, fc1, rh1);
  fc2_k<<<g1(M_*16), 256, 0, stream>>>(rh1, fc2, htmp);

  // ---- m2a + batch reduce ----
  gemm_k<1><<<gg(E2_,128), 256, 0, stream>>>(emb2, m2a_m1, rh1, E2_, 64, 128);
  gemm_k<1><<<gg(E2_,128), 256, 0, stream>>>(rh1, m2a_m2, rh2, E2_, 128, 128);
  dot128_k<<<g1(E2_), 256, 0, stream>>>(rh2, m2a_m3, rout, E2_);
  m2a_k<<<g1(E2_), 256, 0, stream>>>(htmp, mdst, asrc, sh2, m2a_W, rout, af);
  bsum_k<<<g1(N_), 256, 0, stream>>>(af, batch, out);
}

// Round 2
// 1185.976 us; speedup vs baseline: 1.5286x; 1.5286x over previous
//
#include <hip/hip_runtime.h>
#include <math.h>

#define DEVI __device__ __forceinline__

namespace {

constexpr int N_  = 2048;
constexpr int E_  = 32768;
constexpr int E2_ = 65536;
constexpr int M_  = 64000;   // 8 * 20^3

DEVI float sigm(float x)  { return 1.0f/(1.0f+expf(-x)); }
DEVI float geluf(float x) {
  float t = tanhf(0.7978845608028654f*(x + 0.044715f*x*x*x));
  return 0.5f*x*(1.0f+t);
}

// ---------------- utility ----------------
__global__ void zero_k(float* __restrict__ p, int n){
  int i = blockIdx.x*256 + threadIdx.x;
  if (i < n) p[i] = 0.0f;
}

__global__ void meshpos_k(const float* __restrict__ cell, float* __restrict__ mp){
  int m = blockIdx.x*256 + threadIdx.x;
  if (m >= M_) return;
  int b = m/8000, r = m%8000;
  float fx = (float)(r/400)    * 0.05f;
  float fy = (float)((r/20)%20)* 0.05f;
  float fz = (float)(r%20)     * 0.05f;
  const float* c = cell + b*9;
  mp[(size_t)m*3+0] = fx*c[0] + fy*c[3] + fz*c[6];
  mp[(size_t)m*3+1] = fx*c[1] + fy*c[4] + fz*c[7];
  mp[(size_t)m*3+2] = fx*c[2] + fy*c[5] + fz*c[8];
}

// edge geometry: ev = P[pi[e]] - Q[qi[e]]; writes sh (9) and gauss emb (64)
__global__ void edge_geom_k(const float* __restrict__ Ppos, const int* __restrict__ pi,
                            const float* __restrict__ Qpos, const int* __restrict__ qi,
                            float* __restrict__ sh, float* __restrict__ emb, int nE){
  int e = blockIdx.x;
  if (e >= nE) return;
  int lane = threadIdx.x;  // 64
  int a = pi[e], b = qi[e];
  float ex = Ppos[(size_t)a*3+0] - Qpos[(size_t)b*3+0];
  float ey = Ppos[(size_t)a*3+1] - Qpos[(size_t)b*3+1];
  float ez = Ppos[(size_t)a*3+2] - Qpos[(size_t)b*3+2];
  float el = sqrtf(ex*ex+ey*ey+ez*ez) + 1e-8f;
  const float step = 5.0f/63.0f;
  float val = lane * step;               // linspace(0,5,64)
  float d = (el - val)/step;
  emb[(size_t)e*64 + lane] = expf(-d*d) * (8.0f/1.12f);
  if (lane == 0) {
    float x = ex/el, y = ey/el, z = ez/el;
    float* s = sh + (size_t)e*9;
    s[0] = 0.28209479177387814f;
    s[1] = 0.4886025119029199f*y;
    s[2] = 0.4886025119029199f*z;
    s[3] = 0.4886025119029199f*x;
    s[4] = 1.0925484305920792f*x*y;
    s[5] = 1.0925484305920792f*y*z;
    s[6] = 0.31539156525252005f*(3.0f*z*z-1.0f);
    s[7] = 1.0925484305920792f*x*z;
    s[8] = 0.5462742152960396f*(x*x-y*y);
  }
}

__global__ void gather_emb_k(const float* __restrict__ emb, const int* __restrict__ an,
                             float* __restrict__ x16){
  int idx = blockIdx.x*256 + threadIdx.x;
  if (idx >= N_*16) return;
  int n = idx >> 4, f = idx & 15;
  x16[idx] = emb[(size_t)an[n]*16 + f];
}

// ---------------- generic tiled GEMM: C = act(A@B) ----------------
// A: Mr x K row-major, B: K x Nc row-major.  ACT: 0 none, 1 silu
#define BM 64
#define BN 64
#define BK 16
template<int ACT>
__global__ __launch_bounds__(256) void gemm_k(const float* __restrict__ A, const float* __restrict__ B,
                      float* __restrict__ C, int Mr, int K, int Nc){
  __shared__ float As[BK][BM+4];
  __shared__ float Bs[BK][BN+4];
  int tid = threadIdx.x;
  int row0 = blockIdx.y*BM, col0 = blockIdx.x*BN;
  int tx = tid & 15, ty = tid >> 4;
  float acc[4][4] = {};
  for (int k0 = 0; k0 < K; k0 += BK) {
    { int kk = tid & 15; int mloc = tid >> 4;
      int gk = k0 + kk;
      for (int p = 0; p < 4; ++p) {
        int m = mloc + p*16; int gm = row0 + m;
        As[kk][m] = (gm < Mr && gk < K) ? A[(size_t)gm*K + gk] : 0.0f;
      } }
    { int nn = tid & 63; int kl = tid >> 6;
      for (int p = 0; p < 4; ++p) {
        int kk = kl + p*4; int gk = k0 + kk; int gn = col0 + nn;
        Bs[kk][nn] = (gk < K && gn < Nc) ? B[(size_t)gk*Nc + gn] : 0.0f;
      } }
    __syncthreads();
    #pragma unroll
    for (int kk = 0; kk < BK; ++kk) {
      float a[4], b[4];
      #pragma unroll
      for (int i=0;i<4;++i) a[i] = As[kk][ty*4+i];
      #pragma unroll
      for (int j=0;j<4;++j) b[j] = Bs[kk][tx*4+j];
      #pragma unroll
      for (int i=0;i<4;++i)
        #pragma unroll
        for (int j=0;j<4;++j) acc[i][j] += a[i]*b[j];
    }
    __syncthreads();
  }
  for (int i=0;i<4;++i) {
    int gm = row0 + ty*4+i; if (gm >= Mr) continue;
    for (int j=0;j<4;++j) {
      int gn = col0 + tx*4+j; if (gn >= Nc) continue;
      float v = acc[i][j];
      if (ACT==1) v = v/(1.0f+expf(-v));
      C[(size_t)gm*Nc + gn] = v;
    }
  }
}

// ---------------- expanded-GEMM replacement ----------------
// Wt[f*(9*O) + s*O + o] = W[(f*9+s)*O + o]
template<int O>
__global__ void wreshape_k(const float* __restrict__ W, float* __restrict__ Wt, int F){
  int idx = blockIdx.x*256 + threadIdx.x;
  int total = F*9*O;
  if (idx >= total) return;
  int o = idx % O; int s = (idx / O) % 9; int f = idx / (9*O);
  Wt[idx] = W[(size_t)(f*9+s)*O + o];
}

// per-edge: out[dst[e],o] += (sum_s sh[e,s]*Y[src[e], s*O+o]) * rout[e,o]
template<int O>
__global__ void econtract_k(const float* __restrict__ Y, const int* __restrict__ src,
                            const int* __restrict__ dst, const float* __restrict__ SH,
                            const float* __restrict__ rout, float* __restrict__ out,
                            int nE){
  int idx = blockIdx.x*256 + threadIdx.x;
  if (idx >= nE*O) return;
  int e = idx / O, o = idx - e*O;
  const float* sr = SH + (size_t)e*9;
  const float* yr = Y + (size_t)src[e]*(9*O) + o;
  float acc = 0.0f;
  #pragma unroll
  for (int s = 0; s < 9; ++s) acc += sr[s] * yr[s*O];
  atomicAdd(&out[(size_t)dst[e]*O + o], acc * rout[idx]);
}

// ---------------- GCN pieces ----------------
__global__ void normact_k(const float* __restrict__ x, float* __restrict__ y){
  int idx = blockIdx.x*256 + threadIdx.x;
  if (idx >= N_*16) return;
  int n = idx >> 4, r = idx & 15;
  const float* xr = x + (size_t)n*144;
  float* yr = y + (size_t)n*144;
  float s = xr[r];
  yr[r] = s * sigm(fabsf(s));
  float v0 = xr[16+r*3], v1 = xr[16+r*3+1], v2 = xr[16+r*3+2];
  float gv = sigm(sqrtf(v0*v0+v1*v1+v2*v2));
  yr[16+r*3]=v0*gv; yr[16+r*3+1]=v1*gv; yr[16+r*3+2]=v2*gv;
  float t0=xr[64+r*5],t1=xr[64+r*5+1],t2=xr[64+r*5+2],t3=xr[64+r*5+3],t4=xr[64+r*5+4];
  float gt = sigm(sqrtf(t0*t0+t1*t1+t2*t2+t3*t3+t4*t4));
  yr[64+r*5]=t0*gt; yr[64+r*5+1]=t1*gt; yr[64+r*5+2]=t2*gt; yr[64+r*5+3]=t3*gt; yr[64+r*5+4]=t4*gt;
}

// out[n,o] = sum_f xin[n,f]*Wsc[f,o]  (self-connection init before scatter)
__global__ void wscinit_k(const float* __restrict__ xin, const float* __restrict__ Wsc,
                          float* __restrict__ out, int nRows, int Kf, int Of){
  int idx = blockIdx.x*256 + threadIdx.x;
  if (idx >= nRows*Of) return;
  int n = idx / Of, o = idx - n*Of;
  float acc = 0.0f;
  for (int f = 0; f < Kf; ++f) acc += xin[(size_t)n*Kf+f]*Wsc[(size_t)f*Of+o];
  out[idx] = acc;
}

__global__ void sigabs_k(float* __restrict__ x, int n){
  int i = blockIdx.x*256 + threadIdx.x;
  if (i < n) { float v = x[i]; x[i] = v * sigm(fabsf(v)); }
}

// ---------------- FNO ----------------
__global__ void fc0_k(const float* __restrict__ mf, const float* __restrict__ Wt,
                      const float* __restrict__ bb, float* __restrict__ h){
  int idx = blockIdx.x*256 + threadIdx.x;
  if (idx >= M_*16) return;
  int m = idx >> 4, o = idx & 15;
  int r = m % 8000;
  float fx = (float)(r/400)*0.05f, fy = (float)((r/20)%20)*0.05f, fz = (float)(r%20)*0.05f;
  const float* mfr = mf + (size_t)m*32;
  float acc = bb[o];
  #pragma unroll
  for (int j=0;j<32;++j) acc += mfr[j]*Wt[j*16+o];
  acc += fx*Wt[32*16+o] + fy*Wt[33*16+o] + fz*Wt[34*16+o];
  h[idx] = acc;
}

// real->complex DFT along z, keep kz=0..9. out[b][x][y][kz][i]
__global__ void zfwd_k(const float* __restrict__ h, float2* __restrict__ out){
  __shared__ float2 tw[20];
  if (threadIdx.x < 20) { float a = -6.283185307179586f*threadIdx.x/20.0f; tw[threadIdx.x] = make_float2(cosf(a), sinf(a)); }
  __syncthreads();
  int idx = blockIdx.x*256 + threadIdx.x;
  if (idx >= 512000) return;
  int i = idx & 15;
  int kz = (idx >> 4) % 10;
  int bxy = idx / 160;
  const float* hp = h + (size_t)bxy*320 + i;
  float sr=0.0f, si=0.0f; int j=0;
  for (int z=0; z<20; ++z) {
    float v = hp[z*16];
    float2 t = tw[j];
    sr += v*t.x; si += v*t.y;
    j += kz; if (j >= 20) j -= 20;
  }
  out[idx] = make_float2(sr, si);
}

// complex DFT along an axis of length 20 (inner stride innerSz), sign=-1 fwd, +1 inv
__global__ void cdft_k(const float2* __restrict__ in, float2* __restrict__ out,
                       int innerSz, int total, float sign){
  __shared__ float2 tw[20];
  if (threadIdx.x < 20) { float a = sign*6.283185307179586f*threadIdx.x/20.0f; tw[threadIdx.x] = make_float2(cosf(a), sinf(a)); }
  __syncthreads();
  int idx = blockIdx.x*256 + threadIdx.x;
  if (idx >= total) return;
  int inner = idx % innerSz;
  int ko = (idx / innerSz) % 20;
  int outer = idx / (innerSz*20);
  const float2* ip = in + (size_t)outer*20*innerSz + inner;
  float sr=0.0f, si=0.0f; int j=0;
  for (int t=0;t<20;++t) {
    float2 v = ip[(size_t)t*innerSz];
    float2 w = tw[j];
    sr += v.x*w.x - v.y*w.y;
    si += v.x*w.y + v.y*w.x;
    j += ko; if (j >= 20) j -= 20;
  }
  out[idx] = make_float2(sr, si);
}

// channel mix with corner weights. in/out [b][kx][ky][kz][ch]
__global__ void mix_k(const float2* __restrict__ in, float2* __restrict__ out,
                      const float* __restrict__ wr, const float* __restrict__ wi){
  int idx = blockIdx.x*256 + threadIdx.x;
  if (idx >= 512000) return;
  int o = idx & 15;
  int kz = (idx >> 4) % 10;
  int t = idx / 160;                  // (b*20+kx)*20+ky
  int ky = t % 20, kx = (t/20) % 20;
  int c = (kx>=10 ? 1 : 0) + (ky>=10 ? 2 : 0);
  int xx = kx % 10, yy = ky % 10;
  size_t wbase = ((size_t)(c*16)*16 + o)*1000 + xx*100 + yy*10 + kz;
  size_t ibase = (size_t)t*160 + kz*16;
  float sr=0.0f, si=0.0f;
  #pragma unroll
  for (int i=0;i<16;++i) {
    float2 a = in[ibase + i];
    float wrv = wr[wbase + (size_t)i*16000];
    float wiv = wi[wbase + (size_t)i*16000];
    sr += a.x*wrv - a.y*wiv;
    si += a.x*wiv + a.y*wrv;
  }
  out[idx] = make_float2(sr, si);
}

// inverse real transform along z (numpy irfft semantics: Im(bin0) ignored, Nyquist zero)
__global__ void zinv_k(const float2* __restrict__ in, float* __restrict__ spec){
  __shared__ float2 tw[20];
  if (threadIdx.x < 20) { float a = 6.283185307179586f*threadIdx.x/20.0f; tw[threadIdx.x] = make_float2(cosf(a), sinf(a)); }
  __syncthreads();
  int idx = blockIdx.x*256 + threadIdx.x;
  if (idx >= M_*16) return;
  int o = idx & 15;
  int z = (idx >> 4) % 20;
  int bxy = idx / 320;
  const float2* ip = in + (size_t)bxy*160 + o;
  float acc = 0.0f; int j=0;
  for (int kz=0;kz<10;++kz) {
    float2 v = ip[kz*16];
    float2 w = tw[j];
    float re = v.x*w.x - v.y*w.y;
    acc += (kz==0) ? re : 2.0f*re;
    j += z; if (j >= 20) j -= 20;
  }
  spec[idx] = acc * (1.0f/8000.0f);
}

__global__ void pwgelu_k(const float* __restrict__ spec, const float* __restrict__ h,
                         const float* __restrict__ pw, float* __restrict__ out){
  int idx = blockIdx.x*256 + threadIdx.x;
  if (idx >= M_*16) return;
  int m = idx >> 4, o = idx & 15;
  const float* hr = h + (size_t)m*16;
  float acc = spec[idx];
  #pragma unroll
  for (int i=0;i<16;++i) acc += hr[i]*pw[i*16+o];
  out[idx] = geluf(acc);
}

__global__ void ff1g_k(const float* __restrict__ h, const float* __restrict__ Wt, float* __restrict__ out){
  int idx = blockIdx.x*256 + threadIdx.x;
  if (idx >= M_*64) return;
  int m = idx >> 6, j = idx & 63;
  const float* hr = h + (size_t)m*16;
  float acc = 0.0f;
  #pragma unroll
  for (int i=0;i<16;++i) acc += hr[i]*Wt[i*64+j];
  out[idx] = geluf(acc);
}

__global__ void ffout_k(const float* __restrict__ hB, const float* __restrict__ t,
                        const float* __restrict__ Wt, float* __restrict__ h){
  int idx = blockIdx.x*256 + threadIdx.x;
  if (idx >= M_*16) return;
  int m = idx >> 4, o = idx & 15;
  const float* tr = t + (size_t)m*64;
  float acc = hB[idx];
  #pragma unroll
  for (int j=0;j<64;++j) acc += tr[j]*Wt[j*16+o];
  h[idx] = acc;
}

__global__ void fc1g_k(const float* __restrict__ h, const float* __restrict__ Wt, float* __restrict__ out){
  int idx = blockIdx.x*256 + threadIdx.x;
  if (idx >= M_*128) return;
  int m = idx >> 7, j = idx & 127;
  const float* hr = h + (size_t)m*16;
  float acc = 0.0f;
  #pragma unroll
  for (int i=0;i<16;++i) acc += hr[i]*Wt[i*128+j];
  out[idx] = geluf(acc);
}

__global__ void fc2_k(const float* __restrict__ t, const float* __restrict__ Wt, float* __restrict__ out){
  int idx = blockIdx.x*256 + threadIdx.x;
  if (idx >= M_*16) return;
  int m = idx >> 4, o = idx & 15;
  const float* tr = t + (size_t)m*128;
  float acc = 0.0f;
  #pragma unroll
  for (int j=0;j<128;++j) acc += tr[j]*Wt[j*16+o];
  out[idx] = acc;
}

// ---------------- m2a + final ----------------
__global__ void dot128_k(const float* __restrict__ A, const float* __restrict__ w,
                         float* __restrict__ out, int rows){
  int e = blockIdx.x*256 + threadIdx.x;
  if (e >= rows) return;
  const float* ar = A + (size_t)e*128;
  float acc = 0.0f;
  #pragma unroll
  for (int k=0;k<128;++k) acc += ar[k]*w[k];
  out[e] = acc;
}

__global__ void m2a_k(const float* __restrict__ mf2, const int* __restrict__ mdst,
                      const int* __restrict__ asrc, const float* __restrict__ sh2,
                      const float* __restrict__ Wt, const float* __restrict__ rvec,
                      float* __restrict__ af){
  int e = blockIdx.x*256 + threadIdx.x;
  if (e >= E2_) return;
  const float* xr = mf2 + (size_t)mdst[e]*16;
  const float* sr = sh2 + (size_t)e*9;
  float sh[9];
  #pragma unroll
  for (int s=0;s<9;++s) sh[s] = sr[s];
  float acc = 0.0f;
  #pragma unroll
  for (int f=0;f<16;++f) {
    float xv = xr[f];
    float dot = 0.0f;
    #pragma unroll
    for (int s=0;s<9;++s) dot += sh[s]*Wt[f*9+s];
    acc += xv*dot;
  }
  atomicAdd(&af[asrc[e]], acc*rvec[e]);
}

__global__ void bsum_k(const float* __restrict__ af, const int* __restrict__ batch,
                       float* __restrict__ out){
  int n = blockIdx.x*256 + threadIdx.x;
  if (n >= N_) return;
  atomicAdd(&out[batch[n]], af[n]);
}

} // namespace

extern "C" void kernel_launch(void* const* d_in, const int* in_sizes, int n_in,
                              void* d_out, int out_size, void* d_ws, size_t ws_size,
                              hipStream_t stream) {
  (void)in_sizes; (void)n_in; (void)out_size; (void)ws_size;
  const float* pos   = (const float*)d_in[0];
  const float* cell  = (const float*)d_in[1];
  const int*   an    = (const int*)d_in[2];
  const int*   batch = (const int*)d_in[3];
  const int*   esrc  = (const int*)d_in[4];
  const int*   edst  = (const int*)d_in[5];
  const int*   asrc  = (const int*)d_in[6];
  const int*   mdst  = (const int*)d_in[7];
  const float* emb   = (const float*)d_in[8];
  const float* g0_W  = (const float*)d_in[9];
  const float* g0_Wsc= (const float*)d_in[10];
  const float* g0_m1 = (const float*)d_in[11];
  const float* g0_m2 = (const float*)d_in[12];
  const float* g0_m3 = (const float*)d_in[13];
  const float* g12_W = (const float*)d_in[14];
  const float* g12_Wsc=(const float*)d_in[15];
  const float* g12_m1= (const float*)d_in[16];
  const float* g12_m2= (const float*)d_in[17];
  const float* g12_m3= (const float*)d_in[18];
  const float* a2m_W = (const float*)d_in[19];
  const float* a2m_m1= (const float*)d_in[20];
  const float* a2m_m2= (const float*)d_in[21];
  const float* a2m_m3= (const float*)d_in[22];
  const float* m2a_W = (const float*)d_in[23];
  const float* m2a_m1= (const float*)d_in[24];
  const float* m2a_m2= (const float*)d_in[25];
  const float* m2a_m3= (const float*)d_in[26];
  const float* fc0_W = (const float*)d_in[27];
  const float* fc0_b = (const float*)d_in[28];
  const float* sw_r  = (const float*)d_in[29];
  const float* sw_i  = (const float*)d_in[30];
  const float* pw    = (const float*)d_in[31];
  const float* ff1   = (const float*)d_in[32];
  const float* ff2   = (const float*)d_in[33];
  const float* fc1   = (const float*)d_in[34];
  const float* fc2   = (const float*)d_in[35];
  float* out = (float*)d_out;

  float* Wp = (float*)d_ws;
  size_t off = 0;
  auto alloc = [&](size_t n){ float* p = Wp + off; off += n; return p; };
  float* meshpos = alloc((size_t)M_*3);
  float* she   = alloc((size_t)E_*9);
  float* embe  = alloc((size_t)E_*64);
  float* sh2   = alloc((size_t)E2_*9);
  float* emb2  = alloc((size_t)E2_*64);
  float* x16   = alloc((size_t)N_*16);
  float* xatom = alloc((size_t)N_*144);
  float* xact  = alloc((size_t)N_*144);
  float* rh1   = alloc((size_t)E2_*128);
  float* rh2   = alloc((size_t)E2_*128);
  float* rout  = alloc((size_t)E_*144);
  float* Wt    = alloc((size_t)144*1296);      // reshaped expanded weights
  float* Yg    = alloc((size_t)N_*1296);       // per-atom Y (also used for a2m: N_*288)
  float* mf    = alloc((size_t)M_*32);
  float* hbuf  = alloc((size_t)M_*16);
  float* htmp  = alloc((size_t)M_*16);
  float* htmp2 = alloc((size_t)M_*16);
  float2* cA   = (float2*)alloc(1024000);
  float2* cB   = (float2*)alloc(1024000);
  float* af    = alloc((size_t)N_);

  auto g1 = [](int n){ return dim3((unsigned)((n+255)/256)); };
  auto gg = [](int Mr, int Nc){ return dim3((unsigned)((Nc+63)/64), (unsigned)((Mr+63)/64)); };

  // zero accumulators
  zero_k<<<g1(8), 256, 0, stream>>>(out, 8);
  zero_k<<<g1(N_), 256, 0, stream>>>(af, N_);
  zero_k<<<g1(M_*32), 256, 0, stream>>>(mf, M_*32);

  // geometry
  meshpos_k<<<g1(M_), 256, 0, stream>>>(cell, meshpos);
  edge_geom_k<<<E_, 64, 0, stream>>>(pos, esrc, pos, edst, she, embe, E_);
  edge_geom_k<<<E2_, 64, 0, stream>>>(meshpos, mdst, pos, asrc, sh2, emb2, E2_);
  gather_emb_k<<<g1(N_*16), 256, 0, stream>>>(emb, an, x16);

  // ---- g0 ----
  gemm_k<1><<<gg(E_,128), 256, 0, stream>>>(embe, g0_m1, rh1, E_, 64, 128);
  gemm_k<1><<<gg(E_,128), 256, 0, stream>>>(rh1, g0_m2, rh2, E_, 128, 128);
  gemm_k<0><<<gg(E_,144), 256, 0, stream>>>(rh2, g0_m3, rout, E_, 128, 144);
  wreshape_k<144><<<g1(16*9*144), 256, 0, stream>>>(g0_W, Wt, 16);
  gemm_k<0><<<gg(N_,1296), 256, 0, stream>>>(x16, Wt, Yg, N_, 16, 1296);
  wscinit_k<<<g1(N_*144), 256, 0, stream>>>(x16, g0_Wsc, xatom, N_, 16, 144);
  econtract_k<144><<<g1(E_*144), 256, 0, stream>>>(Yg, esrc, edst, she, rout, xatom, E_);

  // ---- g12 x2 ----
  for (int i = 0; i < 2; ++i) {
    normact_k<<<g1(N_*16), 256, 0, stream>>>(xatom, xact);
    gemm_k<1><<<gg(E_,128), 256, 0, stream>>>(embe, g12_m1 + (size_t)i*64*128, rh1, E_, 64, 128);
    gemm_k<1><<<gg(E_,128), 256, 0, stream>>>(rh1, g12_m2 + (size_t)i*128*128, rh2, E_, 128, 128);
    gemm_k<0><<<gg(E_,144), 256, 0, stream>>>(rh2, g12_m3 + (size_t)i*128*144, rout, E_, 128, 144);
    wreshape_k<144><<<g1(144*9*144), 256, 0, stream>>>(g12_W + (size_t)i*1296*144, Wt, 144);
    gemm_k<0><<<gg(N_,1296), 256, 0, stream>>>(xact, Wt, Yg, N_, 144, 1296);
    wscinit_k<<<g1(N_*144), 256, 0, stream>>>(xact, g12_Wsc + (size_t)i*144*144, xatom, N_, 144, 144);
    econtract_k<144><<<g1(E_*144), 256, 0, stream>>>(Yg, esrc, edst, she, rout, xatom, E_);
  }

  // ---- a2m ----
  gemm_k<1><<<gg(E2_,128), 256, 0, stream>>>(emb2, a2m_m1, rh1, E2_, 64, 128);
  gemm_k<1><<<gg(E2_,128), 256, 0, stream>>>(rh1, a2m_m2, rh2, E2_, 128, 128);
  gemm_k<0><<<gg(E2_,32), 256, 0, stream>>>(rh2, a2m_m3, rout, E2_, 128, 32);
  wreshape_k<32><<<g1(144*9*32), 256, 0, stream>>>(a2m_W, Wt, 144);
  gemm_k<0><<<gg(N_,288), 256, 0, stream>>>(xatom, Wt, Yg, N_, 144, 288);
  econtract_k<32><<<g1(E2_*32), 256, 0, stream>>>(Yg, asrc, mdst, sh2, rout, mf, E2_);
  sigabs_k<<<g1(M_*32), 256, 0, stream>>>(mf, M_*32);

  // ---- FNO ----
  fc0_k<<<g1(M_*16), 256, 0, stream>>>(mf, fc0_W, fc0_b, hbuf);
  for (int l = 0; l < 3; ++l) {
    zfwd_k<<<g1(512000), 256, 0, stream>>>(hbuf, cA);
    cdft_k<<<g1(512000), 256, 0, stream>>>(cA, cB, 160, 512000, -1.0f);  // y fwd
    cdft_k<<<g1(512000), 256, 0, stream>>>(cB, cA, 3200, 512000, -1.0f); // x fwd
    mix_k<<<g1(512000), 256, 0, stream>>>(cA, cB, sw_r + (size_t)l*1024000, sw_i + (size_t)l*1024000);
    cdft_k<<<g1(512000), 256, 0, stream>>>(cB, cA, 3200, 512000, 1.0f);  // x inv
    cdft_k<<<g1(512000), 256, 0, stream>>>(cA, cB, 160, 512000, 1.0f);   // y inv
    zinv_k<<<g1(M_*16), 256, 0, stream>>>(cB, htmp);
    pwgelu_k<<<g1(M_*16), 256, 0, stream>>>(htmp, hbuf, pw + (size_t)l*256, htmp2);
    ff1g_k<<<g1(M_*64), 256, 0, stream>>>(htmp2, ff1 + (size_t)l*1024, rh1);
    ffout_k<<<g1(M_*16), 256, 0, stream>>>(htmp2, rh1, ff2 + (size_t)l*1024, hbuf);
  }
  fc1g_k<<<g1(M_*128), 256, 0, stream>>>(hbuf, fc1, rh1);
  fc2_k<<<g1(M_*16), 256, 0, stream>>>(rh1, fc2, htmp);

  // ---- m2a + batch reduce ----
  gemm_k<1><<<gg(E2_,128), 256, 0, stream>>>(emb2, m2a_m1, rh1, E2_, 64, 128);
  gemm_k<1><<<gg(E2_,128), 256, 0, stream>>>(rh1, m2a_m2, rh2, E2_, 128, 128);
  dot128_k<<<g1(E2_), 256, 0, stream>>>(rh2, m2a_m3, rout, E2_);
  m2a_k<<<g1(E2_), 256, 0, stream>>>(htmp, mdst, asrc, sh2, m2a_W, rout, af);
  bsum_k<<<g1(N_), 256, 0, stream>>>(af, batch, out);
}

// Round 3
// 963.814 us; speedup vs baseline: 1.8809x; 1.2305x over previous
//
#include <hip/hip_runtime.h>
#include <math.h>

#define DEVI __device__ __forceinline__

namespace {

constexpr int N_  = 2048;
constexpr int E_  = 32768;
constexpr int E2_ = 65536;
constexpr int M_  = 64000;   // 8 * 20^3
constexpr int NT_ = 8192;    // radial table resolution
constexpr float TMAX_ = 5.5f;
constexpr float TH_ = TMAX_ / NT_;

DEVI float sigm(float x)  { return 1.0f/(1.0f+expf(-x)); }
DEVI float geluf(float x) {
  float t = tanhf(0.7978845608028654f*(x + 0.044715f*x*x*x));
  return 0.5f*x*(1.0f+t);
}

// ---------------- utility ----------------
__global__ void zero_k(float* __restrict__ p, int n){
  int i = blockIdx.x*256 + threadIdx.x;
  if (i < n) p[i] = 0.0f;
}

__global__ void meshpos_k(const float* __restrict__ cell, float* __restrict__ mp){
  int m = blockIdx.x*256 + threadIdx.x;
  if (m >= M_) return;
  int b = m/8000, r = m%8000;
  float fx = (float)(r/400)    * 0.05f;
  float fy = (float)((r/20)%20)* 0.05f;
  float fz = (float)(r%20)     * 0.05f;
  const float* c = cell + b*9;
  mp[(size_t)m*3+0] = fx*c[0] + fy*c[3] + fz*c[6];
  mp[(size_t)m*3+1] = fx*c[1] + fy*c[4] + fz*c[7];
  mp[(size_t)m*3+2] = fx*c[2] + fy*c[5] + fz*c[8];
}

// edge geometry: ev = P[pi[e]] - Q[qi[e]]; writes sh (9) and el (1)
__global__ void edge_geom2_k(const float* __restrict__ Ppos, const int* __restrict__ pi,
                             const float* __restrict__ Qpos, const int* __restrict__ qi,
                             float* __restrict__ sh, float* __restrict__ el_out, int nE){
  int e = blockIdx.x*256 + threadIdx.x;
  if (e >= nE) return;
  int a = pi[e], b = qi[e];
  float ex = Ppos[(size_t)a*3+0] - Qpos[(size_t)b*3+0];
  float ey = Ppos[(size_t)a*3+1] - Qpos[(size_t)b*3+1];
  float ez = Ppos[(size_t)a*3+2] - Qpos[(size_t)b*3+2];
  float el = sqrtf(ex*ex+ey*ey+ez*ez) + 1e-8f;
  el_out[e] = el;
  float x = ex/el, y = ey/el, z = ez/el;
  float* s = sh + (size_t)e*9;
  s[0] = 0.28209479177387814f;
  s[1] = 0.4886025119029199f*y;
  s[2] = 0.4886025119029199f*z;
  s[3] = 0.4886025119029199f*x;
  s[4] = 1.0925484305920792f*x*y;
  s[5] = 1.0925484305920792f*y*z;
  s[6] = 0.31539156525252005f*(3.0f*z*z-1.0f);
  s[7] = 1.0925484305920792f*x*z;
  s[8] = 0.5462742152960396f*(x*x-y*y);
}

__global__ void gather_emb_k(const float* __restrict__ emb, const int* __restrict__ an,
                             float* __restrict__ x16){
  int idx = blockIdx.x*256 + threadIdx.x;
  if (idx >= N_*16) return;
  int n = idx >> 4, f = idx & 15;
  x16[idx] = emb[(size_t)an[n]*16 + f];
}

// ---------------- radial tables ----------------
struct PadArgs { const float* src[5]; int NO[5]; };
__global__ void padw_k(PadArgs a, float* __restrict__ dst){
  int idx = blockIdx.x*256 + threadIdx.x;
  if (idx >= 5*128*160) return;
  int c = idx/(128*160); int rem = idx%(128*160); int k = rem/160, o = rem%160;
  int no = a.NO[c];
  dst[idx] = (o < no) ? a.src[c][(size_t)k*no + o] : 0.0f;
}

struct TabArgs {
  const float* m1[5];
  const float* m2[5];
  const float* w3p[5];   // padded 128x160
  float* T[5];
  int NO[5];
};

// fused 3-layer radial MLP evaluated on the el-sample grid; one chain per blockIdx.y
__global__ __launch_bounds__(256) void table_k(TabArgs args){
  int chain = blockIdx.y;
  int row0 = blockIdx.x*32;
  __shared__ float Es[32][65];
  __shared__ float H1[32][129];
  __shared__ float H2[32][129];
  int tid = threadIdx.x;
  const float step = 5.0f/63.0f;
  for (int t = tid; t < 32*64; t += 256) {
    int rr = t >> 6, kk = t & 63;
    float el = (row0 + rr) * TH_;
    float d = (el - kk*step)/step;
    Es[rr][kk] = expf(-d*d)*(8.0f/1.12f);
  }
  __syncthreads();
  int r = tid & 31, g = tid >> 5;   // 8 col-groups
  // layer 1: 64 -> 128, silu
  {
    const float* W1 = args.m1[chain];
    float acc[16] = {};
    for (int k = 0; k < 64; ++k) {
      float x = Es[r][k];
      const float4* w = (const float4*)(W1 + (size_t)k*128 + g*16);
      #pragma unroll
      for (int c = 0; c < 4; ++c) {
        float4 wv = w[c];
        acc[c*4+0] += x*wv.x; acc[c*4+1] += x*wv.y;
        acc[c*4+2] += x*wv.z; acc[c*4+3] += x*wv.w;
      }
    }
    #pragma unroll
    for (int c = 0; c < 16; ++c) { float v = acc[c]; H1[r][g*16+c] = v*sigm(v); }
  }
  __syncthreads();
  // layer 2: 128 -> 128, silu
  {
    const float* W2 = args.m2[chain];
    float acc[16] = {};
    for (int k = 0; k < 128; ++k) {
      float x = H1[r][k];
      const float4* w = (const float4*)(W2 + (size_t)k*128 + g*16);
      #pragma unroll
      for (int c = 0; c < 4; ++c) {
        float4 wv = w[c];
        acc[c*4+0] += x*wv.x; acc[c*4+1] += x*wv.y;
        acc[c*4+2] += x*wv.z; acc[c*4+3] += x*wv.w;
      }
    }
    #pragma unroll
    for (int c = 0; c < 16; ++c) { float v = acc[c]; H2[r][g*16+c] = v*sigm(v); }
  }
  __syncthreads();
  // layer 3: 128 -> NO (padded 160), linear
  {
    const float* W3 = args.w3p[chain];
    int NO = args.NO[chain];
    float acc[20] = {};
    for (int k = 0; k < 128; ++k) {
      float x = H2[r][k];
      const float4* w = (const float4*)(W3 + (size_t)k*160 + g*20);
      #pragma unroll
      for (int c = 0; c < 5; ++c) {
        float4 wv = w[c];
        acc[c*4+0] += x*wv.x; acc[c*4+1] += x*wv.y;
        acc[c*4+2] += x*wv.z; acc[c*4+3] += x*wv.w;
      }
    }
    float* T = args.T[chain];
    int row = row0 + r;
    #pragma unroll
    for (int c = 0; c < 20; ++c) {
      int col = g*20 + c;
      if (col < NO) T[(size_t)row*NO + col] = acc[c];
    }
  }
}

DEVI float lerp_tab(const float* __restrict__ T, float el, int O, int o){
  float u = el * (1.0f/TH_);
  u = fminf(u, (float)(NT_-1));
  int i = (int)u; if (i > NT_-2) i = NT_-2;
  float f = u - (float)i;
  float t0 = T[(size_t)i*O + o];
  float t1 = T[(size_t)(i+1)*O + o];
  return t0 + f*(t1 - t0);
}

// ---------------- generic tiled GEMM: C = A@B ----------------
#define BM 64
#define BN 64
#define BK 16
__global__ __launch_bounds__(256) void gemm_k(const float* __restrict__ A, const float* __restrict__ B,
                      float* __restrict__ C, int Mr, int K, int Nc){
  __shared__ float As[BK][BM+4];
  __shared__ float Bs[BK][BN+4];
  int tid = threadIdx.x;
  int row0 = blockIdx.y*BM, col0 = blockIdx.x*BN;
  int tx = tid & 15, ty = tid >> 4;
  float acc[4][4] = {};
  for (int k0 = 0; k0 < K; k0 += BK) {
    { int kk = tid & 15; int mloc = tid >> 4;
      int gk = k0 + kk;
      for (int p = 0; p < 4; ++p) {
        int m = mloc + p*16; int gm = row0 + m;
        As[kk][m] = (gm < Mr && gk < K) ? A[(size_t)gm*K + gk] : 0.0f;
      } }
    { int nn = tid & 63; int kl = tid >> 6;
      for (int p = 0; p < 4; ++p) {
        int kk = kl + p*4; int gk = k0 + kk; int gn = col0 + nn;
        Bs[kk][nn] = (gk < K && gn < Nc) ? B[(size_t)gk*Nc + gn] : 0.0f;
      } }
    __syncthreads();
    #pragma unroll
    for (int kk = 0; kk < BK; ++kk) {
      float a[4], b[4];
      #pragma unroll
      for (int i=0;i<4;++i) a[i] = As[kk][ty*4+i];
      #pragma unroll
      for (int j=0;j<4;++j) b[j] = Bs[kk][tx*4+j];
      #pragma unroll
      for (int i=0;i<4;++i)
        #pragma unroll
        for (int j=0;j<4;++j) acc[i][j] += a[i]*b[j];
    }
    __syncthreads();
  }
  for (int i=0;i<4;++i) {
    int gm = row0 + ty*4+i; if (gm >= Mr) continue;
    for (int j=0;j<4;++j) {
      int gn = col0 + tx*4+j; if (gn >= Nc) continue;
      C[(size_t)gm*Nc + gn] = acc[i][j];
    }
  }
}

// Wt[f*(9*O) + s*O + o] = W[(f*9+s)*O + o]
template<int O>
__global__ void wreshape_k(const float* __restrict__ W, float* __restrict__ Wt, int F){
  int idx = blockIdx.x*256 + threadIdx.x;
  int total = F*9*O;
  if (idx >= total) return;
  int o = idx % O; int s = (idx / O) % 9; int f = idx / (9*O);
  Wt[idx] = W[(size_t)(f*9+s)*O + o];
}

// per-edge: out[dst[e],o] += (sum_s sh[e,s]*Y[src[e], s*O+o]) * lerp(T, el[e], o)
template<int O>
__global__ void econtract_k(const float* __restrict__ Y, const int* __restrict__ src,
                            const int* __restrict__ dst, const float* __restrict__ SH,
                            const float* __restrict__ EL, const float* __restrict__ T,
                            float* __restrict__ out, int nE){
  int idx = blockIdx.x*256 + threadIdx.x;
  if (idx >= nE*O) return;
  int e = idx / O, o = idx - e*O;
  const float* sr = SH + (size_t)e*9;
  const float* yr = Y + (size_t)src[e]*(9*O) + o;
  float acc = 0.0f;
  #pragma unroll
  for (int s = 0; s < 9; ++s) acc += sr[s] * yr[s*O];
  float rv = lerp_tab(T, EL[e], O, o);
  atomicAdd(&out[(size_t)dst[e]*O + o], acc * rv);
}

// ---------------- GCN pieces ----------------
__global__ void normact_k(const float* __restrict__ x, float* __restrict__ y){
  int idx = blockIdx.x*256 + threadIdx.x;
  if (idx >= N_*16) return;
  int n = idx >> 4, r = idx & 15;
  const float* xr = x + (size_t)n*144;
  float* yr = y + (size_t)n*144;
  float s = xr[r];
  yr[r] = s * sigm(fabsf(s));
  float v0 = xr[16+r*3], v1 = xr[16+r*3+1], v2 = xr[16+r*3+2];
  float gv = sigm(sqrtf(v0*v0+v1*v1+v2*v2));
  yr[16+r*3]=v0*gv; yr[16+r*3+1]=v1*gv; yr[16+r*3+2]=v2*gv;
  float t0=xr[64+r*5],t1=xr[64+r*5+1],t2=xr[64+r*5+2],t3=xr[64+r*5+3],t4=xr[64+r*5+4];
  float gt = sigm(sqrtf(t0*t0+t1*t1+t2*t2+t3*t3+t4*t4));
  yr[64+r*5]=t0*gt; yr[64+r*5+1]=t1*gt; yr[64+r*5+2]=t2*gt; yr[64+r*5+3]=t3*gt; yr[64+r*5+4]=t4*gt;
}

__global__ void wscinit_k(const float* __restrict__ xin, const float* __restrict__ Wsc,
                          float* __restrict__ out, int nRows, int Kf, int Of){
  int idx = blockIdx.x*256 + threadIdx.x;
  if (idx >= nRows*Of) return;
  int n = idx / Of, o = idx - n*Of;
  float acc = 0.0f;
  for (int f = 0; f < Kf; ++f) acc += xin[(size_t)n*Kf+f]*Wsc[(size_t)f*Of+o];
  out[idx] = acc;
}

__global__ void sigabs_k(float* __restrict__ x, int n){
  int i = blockIdx.x*256 + threadIdx.x;
  if (i < n) { float v = x[i]; x[i] = v * sigm(fabsf(v)); }
}

// ---------------- FNO ----------------
__global__ void fc0_k(const float* __restrict__ mf, const float* __restrict__ Wt,
                      const float* __restrict__ bb, float* __restrict__ h){
  int idx = blockIdx.x*256 + threadIdx.x;
  if (idx >= M_*16) return;
  int m = idx >> 4, o = idx & 15;
  int r = m % 8000;
  float fx = (float)(r/400)*0.05f, fy = (float)((r/20)%20)*0.05f, fz = (float)(r%20)*0.05f;
  const float* mfr = mf + (size_t)m*32;
  float acc = bb[o];
  #pragma unroll
  for (int j=0;j<32;++j) acc += mfr[j]*Wt[j*16+o];
  acc += fx*Wt[32*16+o] + fy*Wt[33*16+o] + fz*Wt[34*16+o];
  h[idx] = acc;
}

__global__ void zfwd_k(const float* __restrict__ h, float2* __restrict__ out){
  __shared__ float2 tw[20];
  if (threadIdx.x < 20) { float a = -6.283185307179586f*threadIdx.x/20.0f; tw[threadIdx.x] = make_float2(cosf(a), sinf(a)); }
  __syncthreads();
  int idx = blockIdx.x*256 + threadIdx.x;
  if (idx >= 512000) return;
  int i = idx & 15;
  int kz = (idx >> 4) % 10;
  int bxy = idx / 160;
  const float* hp = h + (size_t)bxy*320 + i;
  float sr=0.0f, si=0.0f; int j=0;
  for (int z=0; z<20; ++z) {
    float v = hp[z*16];
    float2 t = tw[j];
    sr += v*t.x; si += v*t.y;
    j += kz; if (j >= 20) j -= 20;
  }
  out[idx] = make_float2(sr, si);
}

__global__ void cdft_k(const float2* __restrict__ in, float2* __restrict__ out,
                       int innerSz, int total, float sign){
  __shared__ float2 tw[20];
  if (threadIdx.x < 20) { float a = sign*6.283185307179586f*threadIdx.x/20.0f; tw[threadIdx.x] = make_float2(cosf(a), sinf(a)); }
  __syncthreads();
  int idx = blockIdx.x*256 + threadIdx.x;
  if (idx >= total) return;
  int inner = idx % innerSz;
  int ko = (idx / innerSz) % 20;
  int outer = idx / (innerSz*20);
  const float2* ip = in + (size_t)outer*20*innerSz + inner;
  float sr=0.0f, si=0.0f; int j=0;
  for (int t=0;t<20;++t) {
    float2 v = ip[(size_t)t*innerSz];
    float2 w = tw[j];
    sr += v.x*w.x - v.y*w.y;
    si += v.x*w.y + v.y*w.x;
    j += ko; if (j >= 20) j -= 20;
  }
  out[idx] = make_float2(sr, si);
}

__global__ void mix_k(const float2* __restrict__ in, float2* __restrict__ out,
                      const float* __restrict__ wr, const float* __restrict__ wi){
  int idx = blockIdx.x*256 + threadIdx.x;
  if (idx >= 512000) return;
  int o = idx & 15;
  int kz = (idx >> 4) % 10;
  int t = idx / 160;                  // (b*20+kx)*20+ky
  int ky = t % 20, kx = (t/20) % 20;
  int c = (kx>=10 ? 1 : 0) + (ky>=10 ? 2 : 0);
  int xx = kx % 10, yy = ky % 10;
  size_t wbase = ((size_t)(c*16)*16 + o)*1000 + xx*100 + yy*10 + kz;
  size_t ibase = (size_t)t*160 + kz*16;
  float sr=0.0f, si=0.0f;
  #pragma unroll
  for (int i=0;i<16;++i) {
    float2 a = in[ibase + i];
    float wrv = wr[wbase + (size_t)i*16000];
    float wiv = wi[wbase + (size_t)i*16000];
    sr += a.x*wrv - a.y*wiv;
    si += a.x*wiv + a.y*wrv;
  }
  out[idx] = make_float2(sr, si);
}

__global__ void zinv_k(const float2* __restrict__ in, float* __restrict__ spec){
  __shared__ float2 tw[20];
  if (threadIdx.x < 20) { float a = 6.283185307179586f*threadIdx.x/20.0f; tw[threadIdx.x] = make_float2(cosf(a), sinf(a)); }
  __syncthreads();
  int idx = blockIdx.x*256 + threadIdx.x;
  if (idx >= M_*16) return;
  int o = idx & 15;
  int z = (idx >> 4) % 20;
  int bxy = idx / 320;
  const float2* ip = in + (size_t)bxy*160 + o;
  float acc = 0.0f; int j=0;
  for (int kz=0;kz<10;++kz) {
    float2 v = ip[kz*16];
    float2 w = tw[j];
    float re = v.x*w.x - v.y*w.y;
    acc += (kz==0) ? re : 2.0f*re;
    j += z; if (j >= 20) j -= 20;
  }
  spec[idx] = acc * (1.0f/8000.0f);
}

__global__ void pwgelu_k(const float* __restrict__ spec, const float* __restrict__ h,
                         const float* __restrict__ pw, float* __restrict__ out){
  int idx = blockIdx.x*256 + threadIdx.x;
  if (idx >= M_*16) return;
  int m = idx >> 4, o = idx & 15;
  const float* hr = h + (size_t)m*16;
  float acc = spec[idx];
  #pragma unroll
  for (int i=0;i<16;++i) acc += hr[i]*pw[i*16+o];
  out[idx] = geluf(acc);
}

__global__ void ff1g_k(const float* __restrict__ h, const float* __restrict__ Wt, float* __restrict__ out){
  int idx = blockIdx.x*256 + threadIdx.x;
  if (idx >= M_*64) return;
  int m = idx >> 6, j = idx & 63;
  const float* hr = h + (size_t)m*16;
  float acc = 0.0f;
  #pragma unroll
  for (int i=0;i<16;++i) acc += hr[i]*Wt[i*64+j];
  out[idx] = geluf(acc);
}

__global__ void ffout_k(const float* __restrict__ hB, const float* __restrict__ t,
                        const float* __restrict__ Wt, float* __restrict__ h){
  int idx = blockIdx.x*256 + threadIdx.x;
  if (idx >= M_*16) return;
  int m = idx >> 4, o = idx & 15;
  const float* tr = t + (size_t)m*64;
  float acc = hB[idx];
  #pragma unroll
  for (int j=0;j<64;++j) acc += tr[j]*Wt[j*16+o];
  h[idx] = acc;
}

__global__ void fc1g_k(const float* __restrict__ h, const float* __restrict__ Wt, float* __restrict__ out){
  int idx = blockIdx.x*256 + threadIdx.x;
  if (idx >= M_*128) return;
  int m = idx >> 7, j = idx & 127;
  const float* hr = h + (size_t)m*16;
  float acc = 0.0f;
  #pragma unroll
  for (int i=0;i<16;++i) acc += hr[i]*Wt[i*128+j];
  out[idx] = geluf(acc);
}

__global__ void fc2_k(const float* __restrict__ t, const float* __restrict__ Wt, float* __restrict__ out){
  int idx = blockIdx.x*256 + threadIdx.x;
  if (idx >= M_*16) return;
  int m = idx >> 4, o = idx & 15;
  const float* tr = t + (size_t)m*128;
  float acc = 0.0f;
  #pragma unroll
  for (int j=0;j<128;++j) acc += tr[j]*Wt[j*16+o];
  out[idx] = acc;
}

// ---------------- m2a + final ----------------
__global__ void m2a_k(const float* __restrict__ mf2, const int* __restrict__ mdst,
                      const int* __restrict__ asrc, const float* __restrict__ sh2,
                      const float* __restrict__ Wt, const float* __restrict__ EL,
                      const float* __restrict__ T, float* __restrict__ af){
  int e = blockIdx.x*256 + threadIdx.x;
  if (e >= E2_) return;
  const float* xr = mf2 + (size_t)mdst[e]*16;
  const float* sr = sh2 + (size_t)e*9;
  float sh[9];
  #pragma unroll
  for (int s=0;s<9;++s) sh[s] = sr[s];
  float acc = 0.0f;
  #pragma unroll
  for (int f=0;f<16;++f) {
    float xv = xr[f];
    float dot = 0.0f;
    #pragma unroll
    for (int s=0;s<9;++s) dot += sh[s]*Wt[f*9+s];
    acc += xv*dot;
  }
  float rv = lerp_tab(T, EL[e], 1, 0);
  atomicAdd(&af[asrc[e]], acc*rv);
}

__global__ void bsum_k(const float* __restrict__ af, const int* __restrict__ batch,
                       float* __restrict__ out){
  int n = blockIdx.x*256 + threadIdx.x;
  if (n >= N_) return;
  atomicAdd(&out[batch[n]], af[n]);
}

} // namespace

extern "C" void kernel_launch(void* const* d_in, const int* in_sizes, int n_in,
                              void* d_out, int out_size, void* d_ws, size_t ws_size,
                              hipStream_t stream) {
  (void)in_sizes; (void)n_in; (void)out_size; (void)ws_size;
  const float* pos   = (const float*)d_in[0];
  const float* cell  = (const float*)d_in[1];
  const int*   an    = (const int*)d_in[2];
  const int*   batch = (const int*)d_in[3];
  const int*   esrc  = (const int*)d_in[4];
  const int*   edst  = (const int*)d_in[5];
  const int*   asrc  = (const int*)d_in[6];
  const int*   mdst  = (const int*)d_in[7];
  const float* emb   = (const float*)d_in[8];
  const float* g0_W  = (const float*)d_in[9];
  const float* g0_Wsc= (const float*)d_in[10];
  const float* g0_m1 = (const float*)d_in[11];
  const float* g0_m2 = (const float*)d_in[12];
  const float* g0_m3 = (const float*)d_in[13];
  const float* g12_W = (const float*)d_in[14];
  const float* g12_Wsc=(const float*)d_in[15];
  const float* g12_m1= (const float*)d_in[16];
  const float* g12_m2= (const float*)d_in[17];
  const float* g12_m3= (const float*)d_in[18];
  const float* a2m_W = (const float*)d_in[19];
  const float* a2m_m1= (const float*)d_in[20];
  const float* a2m_m2= (const float*)d_in[21];
  const float* a2m_m3= (const float*)d_in[22];
  const float* m2a_W = (const float*)d_in[23];
  const float* m2a_m1= (const float*)d_in[24];
  const float* m2a_m2= (const float*)d_in[25];
  const float* m2a_m3= (const float*)d_in[26];
  const float* fc0_W = (const float*)d_in[27];
  const float* fc0_b = (const float*)d_in[28];
  const float* sw_r  = (const float*)d_in[29];
  const float* sw_i  = (const float*)d_in[30];
  const float* pw    = (const float*)d_in[31];
  const float* ff1   = (const float*)d_in[32];
  const float* ff2   = (const float*)d_in[33];
  const float* fc1   = (const float*)d_in[34];
  const float* fc2   = (const float*)d_in[35];
  float* out = (float*)d_out;

  float* Wp = (float*)d_ws;
  size_t off = 0;
  auto alloc = [&](size_t n){ float* p = Wp + off; off += n; return p; };
  float* meshpos = alloc((size_t)M_*3);
  float* she   = alloc((size_t)E_*9);
  float* ELe   = alloc((size_t)E_);
  float* sh2   = alloc((size_t)E2_*9);
  float* EL2   = alloc((size_t)E2_);
  float* x16   = alloc((size_t)N_*16);
  float* xatom = alloc((size_t)N_*144);
  float* xact  = alloc((size_t)N_*144);
  float* rh1   = alloc((size_t)M_*128);          // FNO ff/fc scratch
  float* Wt    = alloc((size_t)144*1296);        // reshaped expanded weights
  float* Yg    = alloc((size_t)N_*1296);         // per-atom Y
  float* mf    = alloc((size_t)M_*32);
  float* hbuf  = alloc((size_t)M_*16);
  float* htmp  = alloc((size_t)M_*16);
  float* htmp2 = alloc((size_t)M_*16);
  float2* cA   = (float2*)alloc(1024000);
  float2* cB   = (float2*)alloc(1024000);
  float* af    = alloc((size_t)N_);
  float* W3p   = alloc((size_t)5*128*160);       // padded layer-3 weights
  float* T0    = alloc((size_t)NT_*144);
  float* T1    = alloc((size_t)NT_*144);
  float* T2    = alloc((size_t)NT_*144);
  float* T3    = alloc((size_t)NT_*32);
  float* T4    = alloc((size_t)NT_*1);

  auto g1 = [](int n){ return dim3((unsigned)((n+255)/256)); };
  auto gg = [](int Mr, int Nc){ return dim3((unsigned)((Nc+63)/64), (unsigned)((Mr+63)/64)); };

  // zero accumulators
  zero_k<<<g1(8), 256, 0, stream>>>(out, 8);
  zero_k<<<g1(N_), 256, 0, stream>>>(af, N_);
  zero_k<<<g1(M_*32), 256, 0, stream>>>(mf, M_*32);

  // geometry
  meshpos_k<<<g1(M_), 256, 0, stream>>>(cell, meshpos);
  edge_geom2_k<<<g1(E_), 256, 0, stream>>>(pos, esrc, pos, edst, she, ELe, E_);
  edge_geom2_k<<<g1(E2_), 256, 0, stream>>>(meshpos, mdst, pos, asrc, sh2, EL2, E2_);
  gather_emb_k<<<g1(N_*16), 256, 0, stream>>>(emb, an, x16);

  // ---- radial tables (5 chains, one fused launch) ----
  {
    PadArgs pa;
    pa.src[0]=g0_m3; pa.src[1]=g12_m3; pa.src[2]=g12_m3+(size_t)128*144; pa.src[3]=a2m_m3; pa.src[4]=m2a_m3;
    pa.NO[0]=144; pa.NO[1]=144; pa.NO[2]=144; pa.NO[3]=32; pa.NO[4]=1;
    padw_k<<<g1(5*128*160), 256, 0, stream>>>(pa, W3p);
    TabArgs ta;
    ta.m1[0]=g0_m1; ta.m1[1]=g12_m1; ta.m1[2]=g12_m1+(size_t)64*128; ta.m1[3]=a2m_m1; ta.m1[4]=m2a_m1;
    ta.m2[0]=g0_m2; ta.m2[1]=g12_m2; ta.m2[2]=g12_m2+(size_t)128*128; ta.m2[3]=a2m_m2; ta.m2[4]=m2a_m2;
    for (int c=0;c<5;++c) ta.w3p[c] = W3p + (size_t)c*128*160;
    ta.T[0]=T0; ta.T[1]=T1; ta.T[2]=T2; ta.T[3]=T3; ta.T[4]=T4;
    ta.NO[0]=144; ta.NO[1]=144; ta.NO[2]=144; ta.NO[3]=32; ta.NO[4]=1;
    table_k<<<dim3(NT_/32, 5), 256, 0, stream>>>(ta);
  }

  // ---- g0 ----
  wreshape_k<144><<<g1(16*9*144), 256, 0, stream>>>(g0_W, Wt, 16);
  gemm_k<<<gg(N_,1296), 256, 0, stream>>>(x16, Wt, Yg, N_, 16, 1296);
  wscinit_k<<<g1(N_*144), 256, 0, stream>>>(x16, g0_Wsc, xatom, N_, 16, 144);
  econtract_k<144><<<g1(E_*144), 256, 0, stream>>>(Yg, esrc, edst, she, ELe, T0, xatom, E_);

  // ---- g12 x2 ----
  for (int i = 0; i < 2; ++i) {
    normact_k<<<g1(N_*16), 256, 0, stream>>>(xatom, xact);
    wreshape_k<144><<<g1(144*9*144), 256, 0, stream>>>(g12_W + (size_t)i*1296*144, Wt, 144);
    gemm_k<<<gg(N_,1296), 256, 0, stream>>>(xact, Wt, Yg, N_, 144, 1296);
    wscinit_k<<<g1(N_*144), 256, 0, stream>>>(xact, g12_Wsc + (size_t)i*144*144, xatom, N_, 144, 144);
    econtract_k<144><<<g1(E_*144), 256, 0, stream>>>(Yg, esrc, edst, she, ELe, (i==0)?T1:T2, xatom, E_);
  }

  // ---- a2m ----
  wreshape_k<32><<<g1(144*9*32), 256, 0, stream>>>(a2m_W, Wt, 144);
  gemm_k<<<gg(N_,288), 256, 0, stream>>>(xatom, Wt, Yg, N_, 144, 288);
  econtract_k<32><<<g1(E2_*32), 256, 0, stream>>>(Yg, asrc, mdst, sh2, EL2, T3, mf, E2_);
  sigabs_k<<<g1(M_*32), 256, 0, stream>>>(mf, M_*32);

  // ---- FNO ----
  fc0_k<<<g1(M_*16), 256, 0, stream>>>(mf, fc0_W, fc0_b, hbuf);
  for (int l = 0; l < 3; ++l) {
    zfwd_k<<<g1(512000), 256, 0, stream>>>(hbuf, cA);
    cdft_k<<<g1(512000), 256, 0, stream>>>(cA, cB, 160, 512000, -1.0f);  // y fwd
    cdft_k<<<g1(512000), 256, 0, stream>>>(cB, cA, 3200, 512000, -1.0f); // x fwd
    mix_k<<<g1(512000), 256, 0, stream>>>(cA, cB, sw_r + (size_t)l*1024000, sw_i + (size_t)l*1024000);
    cdft_k<<<g1(512000), 256, 0, stream>>>(cB, cA, 3200, 512000, 1.0f);  // x inv
    cdft_k<<<g1(512000), 256, 0, stream>>>(cA, cB, 160, 512000, 1.0f);   // y inv
    zinv_k<<<g1(M_*16), 256, 0, stream>>>(cB, htmp);
    pwgelu_k<<<g1(M_*16), 256, 0, stream>>>(htmp, hbuf, pw + (size_t)l*256, htmp2);
    ff1g_k<<<g1(M_*64), 256, 0, stream>>>(htmp2, ff1 + (size_t)l*1024, rh1);
    ffout_k<<<g1(M_*16), 256, 0, stream>>>(htmp2, rh1, ff2 + (size_t)l*1024, hbuf);
  }
  fc1g_k<<<g1(M_*128), 256, 0, stream>>>(hbuf, fc1, rh1);
  fc2_k<<<g1(M_*16), 256, 0, stream>>>(rh1, fc2, htmp);

  // ---- m2a + batch reduce ----
  m2a_k<<<g1(E2_), 256, 0, stream>>>(htmp, mdst, asrc, sh2, m2a_W, EL2, T4, af);
  bsum_k<<<g1(N_), 256, 0, stream>>>(af, batch, out);
}

// Round 4
// 805.270 us; speedup vs baseline: 2.2512x; 1.1969x over previous
//
#include <hip/hip_runtime.h>
#include <math.h>

#define DEVI __device__ __forceinline__

namespace {

constexpr int N_  = 2048;
constexpr int E_  = 32768;
constexpr int E2_ = 65536;
constexpr int M_  = 64000;   // 8 * 20^3
constexpr int NT_ = 4096;    // radial table resolution
constexpr float TMAX_ = 5.5f;
constexpr float TH_ = TMAX_ / NT_;

DEVI float sigm(float x)  { return 1.0f/(1.0f+expf(-x)); }
DEVI float geluf(float x) {
  float t = tanhf(0.7978845608028654f*(x + 0.044715f*x*x*x));
  return 0.5f*x*(1.0f+t);
}

// ---------------- utility ----------------
__global__ void zero_k(float* __restrict__ p, int n){
  int i = blockIdx.x*256 + threadIdx.x;
  if (i < n) p[i] = 0.0f;
}

__global__ void meshpos_k(const float* __restrict__ cell, float* __restrict__ mp){
  int m = blockIdx.x*256 + threadIdx.x;
  if (m >= M_) return;
  int b = m/8000, r = m%8000;
  float fx = (float)(r/400)    * 0.05f;
  float fy = (float)((r/20)%20)* 0.05f;
  float fz = (float)(r%20)     * 0.05f;
  const float* c = cell + b*9;
  mp[(size_t)m*3+0] = fx*c[0] + fy*c[3] + fz*c[6];
  mp[(size_t)m*3+1] = fx*c[1] + fy*c[4] + fz*c[7];
  mp[(size_t)m*3+2] = fx*c[2] + fy*c[5] + fz*c[8];
}

// edge geometry: ev = P[pi[e]] - Q[qi[e]]; writes sh (9) and el (1)
__global__ void edge_geom2_k(const float* __restrict__ Ppos, const int* __restrict__ pi,
                             const float* __restrict__ Qpos, const int* __restrict__ qi,
                             float* __restrict__ sh, float* __restrict__ el_out, int nE){
  int e = blockIdx.x*256 + threadIdx.x;
  if (e >= nE) return;
  int a = pi[e], b = qi[e];
  float ex = Ppos[(size_t)a*3+0] - Qpos[(size_t)b*3+0];
  float ey = Ppos[(size_t)a*3+1] - Qpos[(size_t)b*3+1];
  float ez = Ppos[(size_t)a*3+2] - Qpos[(size_t)b*3+2];
  float el = sqrtf(ex*ex+ey*ey+ez*ez) + 1e-8f;
  el_out[e] = el;
  float x = ex/el, y = ey/el, z = ez/el;
  float* s = sh + (size_t)e*9;
  s[0] = 0.28209479177387814f;
  s[1] = 0.4886025119029199f*y;
  s[2] = 0.4886025119029199f*z;
  s[3] = 0.4886025119029199f*x;
  s[4] = 1.0925484305920792f*x*y;
  s[5] = 1.0925484305920792f*y*z;
  s[6] = 0.31539156525252005f*(3.0f*z*z-1.0f);
  s[7] = 1.0925484305920792f*x*z;
  s[8] = 0.5462742152960396f*(x*x-y*y);
}

__global__ void gather_emb_k(const float* __restrict__ emb, const int* __restrict__ an,
                             float* __restrict__ x16){
  int idx = blockIdx.x*256 + threadIdx.x;
  if (idx >= N_*16) return;
  int n = idx >> 4, f = idx & 15;
  x16[idx] = emb[(size_t)an[n]*16 + f];
}

// ---------------- radial tables ----------------
// Es[r][k] = gauss(r*TH)[k], r in [0,NT), k in [0,64)
__global__ void es_k(float* __restrict__ Es){
  int idx = blockIdx.x*256 + threadIdx.x;
  if (idx >= NT_*64) return;
  int r = idx >> 6, k = idx & 63;
  const float step = 5.0f/63.0f;
  float d = (r*TH_ - k*step)/step;
  Es[idx] = expf(-d*d)*(8.0f/1.12f);
}

DEVI float lerp_tab(const float* __restrict__ T, float el, int O, int o){
  float u = el * (1.0f/TH_);
  u = fminf(u, (float)(NT_-1));
  int i = (int)u; if (i > NT_-2) i = NT_-2;
  float f = u - (float)i;
  float t0 = T[(size_t)i*O + o];
  float t1 = T[(size_t)(i+1)*O + o];
  return t0 + f*(t1 - t0);
}

// ---------------- tiled GEMM ----------------
#define BM 64
#define BN 64
#define BK 16

// batched (blockIdx.z = chain) GEMM: C_c = act(A_c @ B_c), Mr = NT_
struct BG {
  const float* A[5]; const float* B[5]; float* C[5];
  int K; int Nc[5];
};
template<int ACT>
__global__ __launch_bounds__(256) void bgemm_k(BG args){
  int chain = blockIdx.z;
  const float* A = args.A[chain];
  const float* Bm = args.B[chain];
  float* C = args.C[chain];
  int K = args.K, Nc = args.Nc[chain];
  int row0 = blockIdx.y*BM, col0 = blockIdx.x*BN;
  if (col0 >= Nc) return;
  __shared__ float As[BK][BM+4];
  __shared__ float Bs[BK][BN+4];
  int tid = threadIdx.x;
  int tx = tid & 15, ty = tid >> 4;
  float acc[4][4] = {};
  for (int k0 = 0; k0 < K; k0 += BK) {
    { int kk = tid & 15; int mloc = tid >> 4;
      int gk = k0 + kk;
      for (int p = 0; p < 4; ++p) {
        int m = mloc + p*16; int gm = row0 + m;
        As[kk][m] = A[(size_t)gm*K + gk];
      } }
    { int nn = tid & 63; int kl = tid >> 6;
      for (int p = 0; p < 4; ++p) {
        int kk = kl + p*4; int gk = k0 + kk; int gn = col0 + nn;
        Bs[kk][nn] = (gn < Nc) ? Bm[(size_t)gk*Nc + gn] : 0.0f;
      } }
    __syncthreads();
    #pragma unroll
    for (int kk = 0; kk < BK; ++kk) {
      float a[4], b[4];
      #pragma unroll
      for (int i=0;i<4;++i) a[i] = As[kk][ty*4+i];
      #pragma unroll
      for (int j=0;j<4;++j) b[j] = Bs[kk][tx*4+j];
      #pragma unroll
      for (int i=0;i<4;++i)
        #pragma unroll
        for (int j=0;j<4;++j) acc[i][j] += a[i]*b[j];
    }
    __syncthreads();
  }
  for (int i=0;i<4;++i) {
    int gm = row0 + ty*4+i;
    for (int j=0;j<4;++j) {
      int gn = col0 + tx*4+j; if (gn >= Nc) continue;
      float v = acc[i][j];
      if (ACT==1) v = v*sigm(v);
      C[(size_t)gm*Nc + gn] = v;
    }
  }
}

__global__ __launch_bounds__(256) void gemm_k(const float* __restrict__ A, const float* __restrict__ B,
                      float* __restrict__ C, int Mr, int K, int Nc){
  __shared__ float As[BK][BM+4];
  __shared__ float Bs[BK][BN+4];
  int tid = threadIdx.x;
  int row0 = blockIdx.y*BM, col0 = blockIdx.x*BN;
  int tx = tid & 15, ty = tid >> 4;
  float acc[4][4] = {};
  for (int k0 = 0; k0 < K; k0 += BK) {
    { int kk = tid & 15; int mloc = tid >> 4;
      int gk = k0 + kk;
      for (int p = 0; p < 4; ++p) {
        int m = mloc + p*16; int gm = row0 + m;
        As[kk][m] = (gm < Mr && gk < K) ? A[(size_t)gm*K + gk] : 0.0f;
      } }
    { int nn = tid & 63; int kl = tid >> 6;
      for (int p = 0; p < 4; ++p) {
        int kk = kl + p*4; int gk = k0 + kk; int gn = col0 + nn;
        Bs[kk][nn] = (gk < K && gn < Nc) ? B[(size_t)gk*Nc + gn] : 0.0f;
      } }
    __syncthreads();
    #pragma unroll
    for (int kk = 0; kk < BK; ++kk) {
      float a[4], b[4];
      #pragma unroll
      for (int i=0;i<4;++i) a[i] = As[kk][ty*4+i];
      #pragma unroll
      for (int j=0;j<4;++j) b[j] = Bs[kk][tx*4+j];
      #pragma unroll
      for (int i=0;i<4;++i)
        #pragma unroll
        for (int j=0;j<4;++j) acc[i][j] += a[i]*b[j];
    }
    __syncthreads();
  }
  for (int i=0;i<4;++i) {
    int gm = row0 + ty*4+i; if (gm >= Mr) continue;
    for (int j=0;j<4;++j) {
      int gn = col0 + tx*4+j; if (gn >= Nc) continue;
      C[(size_t)gm*Nc + gn] = acc[i][j];
    }
  }
}

// Wt[f*(9*O) + s*O + o] = W[(f*9+s)*O + o]
template<int O>
__global__ void wreshape_k(const float* __restrict__ W, float* __restrict__ Wt, int F){
  int idx = blockIdx.x*256 + threadIdx.x;
  int total = F*9*O;
  if (idx >= total) return;
  int o = idx % O; int s = (idx / O) % 9; int f = idx / (9*O);
  Wt[idx] = W[(size_t)(f*9+s)*O + o];
}

// per-edge: out[dst[e],o] += (sum_s sh[e,s]*Y[src[e], s*O+o]) * lerp(T, el[e], o)
template<int O>
__global__ void econtract_k(const float* __restrict__ Y, const int* __restrict__ src,
                            const int* __restrict__ dst, const float* __restrict__ SH,
                            const float* __restrict__ EL, const float* __restrict__ T,
                            float* __restrict__ out, int nE){
  int idx = blockIdx.x*256 + threadIdx.x;
  if (idx >= nE*O) return;
  int e = idx / O, o = idx - e*O;
  const float* sr = SH + (size_t)e*9;
  const float* yr = Y + (size_t)src[e]*(9*O) + o;
  float acc = 0.0f;
  #pragma unroll
  for (int s = 0; s < 9; ++s) acc += sr[s] * yr[s*O];
  float rv = lerp_tab(T, EL[e], O, o);
  atomicAdd(&out[(size_t)dst[e]*O + o], acc * rv);
}

// ---------------- GCN pieces ----------------
__global__ void normact_k(const float* __restrict__ x, float* __restrict__ y){
  int idx = blockIdx.x*256 + threadIdx.x;
  if (idx >= N_*16) return;
  int n = idx >> 4, r = idx & 15;
  const float* xr = x + (size_t)n*144;
  float* yr = y + (size_t)n*144;
  float s = xr[r];
  yr[r] = s * sigm(fabsf(s));
  float v0 = xr[16+r*3], v1 = xr[16+r*3+1], v2 = xr[16+r*3+2];
  float gv = sigm(sqrtf(v0*v0+v1*v1+v2*v2));
  yr[16+r*3]=v0*gv; yr[16+r*3+1]=v1*gv; yr[16+r*3+2]=v2*gv;
  float t0=xr[64+r*5],t1=xr[64+r*5+1],t2=xr[64+r*5+2],t3=xr[64+r*5+3],t4=xr[64+r*5+4];
  float gt = sigm(sqrtf(t0*t0+t1*t1+t2*t2+t3*t3+t4*t4));
  yr[64+r*5]=t0*gt; yr[64+r*5+1]=t1*gt; yr[64+r*5+2]=t2*gt; yr[64+r*5+3]=t3*gt; yr[64+r*5+4]=t4*gt;
}

__global__ void wscinit_k(const float* __restrict__ xin, const float* __restrict__ Wsc,
                          float* __restrict__ out, int nRows, int Kf, int Of){
  int idx = blockIdx.x*256 + threadIdx.x;
  if (idx >= nRows*Of) return;
  int n = idx / Of, o = idx - n*Of;
  float acc = 0.0f;
  for (int f = 0; f < Kf; ++f) acc += xin[(size_t)n*Kf+f]*Wsc[(size_t)f*Of+o];
  out[idx] = acc;
}

__global__ void sigabs_k(float* __restrict__ x, int n){
  int i = blockIdx.x*256 + threadIdx.x;
  if (i < n) { float v = x[i]; x[i] = v * sigm(fabsf(v)); }
}

// ---------------- FNO ----------------
__global__ void fc0_k(const float* __restrict__ mf, const float* __restrict__ Wt,
                      const float* __restrict__ bb, float* __restrict__ h){
  int idx = blockIdx.x*256 + threadIdx.x;
  if (idx >= M_*16) return;
  int m = idx >> 4, o = idx & 15;
  int r = m % 8000;
  float fx = (float)(r/400)*0.05f, fy = (float)((r/20)%20)*0.05f, fz = (float)(r%20)*0.05f;
  const float* mfr = mf + (size_t)m*32;
  float acc = bb[o];
  #pragma unroll
  for (int j=0;j<32;++j) acc += mfr[j]*Wt[j*16+o];
  acc += fx*Wt[32*16+o] + fy*Wt[33*16+o] + fz*Wt[34*16+o];
  h[idx] = acc;
}

__global__ void zfwd_k(const float* __restrict__ h, float2* __restrict__ out){
  __shared__ float2 tw[20];
  if (threadIdx.x < 20) { float a = -6.283185307179586f*threadIdx.x/20.0f; tw[threadIdx.x] = make_float2(cosf(a), sinf(a)); }
  __syncthreads();
  int idx = blockIdx.x*256 + threadIdx.x;
  if (idx >= 512000) return;
  int i = idx & 15;
  int kz = (idx >> 4) % 10;
  int bxy = idx / 160;
  const float* hp = h + (size_t)bxy*320 + i;
  float sr=0.0f, si=0.0f; int j=0;
  for (int z=0; z<20; ++z) {
    float v = hp[z*16];
    float2 t = tw[j];
    sr += v*t.x; si += v*t.y;
    j += kz; if (j >= 20) j -= 20;
  }
  out[idx] = make_float2(sr, si);
}

__global__ void cdft_k(const float2* __restrict__ in, float2* __restrict__ out,
                       int innerSz, int total, float sign){
  __shared__ float2 tw[20];
  if (threadIdx.x < 20) { float a = sign*6.283185307179586f*threadIdx.x/20.0f; tw[threadIdx.x] = make_float2(cosf(a), sinf(a)); }
  __syncthreads();
  int idx = blockIdx.x*256 + threadIdx.x;
  if (idx >= total) return;
  int inner = idx % innerSz;
  int ko = (idx / innerSz) % 20;
  int outer = idx / (innerSz*20);
  const float2* ip = in + (size_t)outer*20*innerSz + inner;
  float sr=0.0f, si=0.0f; int j=0;
  for (int t=0;t<20;++t) {
    float2 v = ip[(size_t)t*innerSz];
    float2 w = tw[j];
    sr += v.x*w.x - v.y*w.y;
    si += v.x*w.y + v.y*w.x;
    j += ko; if (j >= 20) j -= 20;
  }
  out[idx] = make_float2(sr, si);
}

__global__ void mix_k(const float2* __restrict__ in, float2* __restrict__ out,
                      const float* __restrict__ wr, const float* __restrict__ wi){
  int idx = blockIdx.x*256 + threadIdx.x;
  if (idx >= 512000) return;
  int o = idx & 15;
  int kz = (idx >> 4) % 10;
  int t = idx / 160;                  // (b*20+kx)*20+ky
  int ky = t % 20, kx = (t/20) % 20;
  int c = (kx>=10 ? 1 : 0) + (ky>=10 ? 2 : 0);
  int xx = kx % 10, yy = ky % 10;
  size_t wbase = ((size_t)(c*16)*16 + o)*1000 + xx*100 + yy*10 + kz;
  size_t ibase = (size_t)t*160 + kz*16;
  float sr=0.0f, si=0.0f;
  #pragma unroll
  for (int i=0;i<16;++i) {
    float2 a = in[ibase + i];
    float wrv = wr[wbase + (size_t)i*16000];
    float wiv = wi[wbase + (size_t)i*16000];
    sr += a.x*wrv - a.y*wiv;
    si += a.x*wiv + a.y*wrv;
  }
  out[idx] = make_float2(sr, si);
}

__global__ void zinv_k(const float2* __restrict__ in, float* __restrict__ spec){
  __shared__ float2 tw[20];
  if (threadIdx.x < 20) { float a = 6.283185307179586f*threadIdx.x/20.0f; tw[threadIdx.x] = make_float2(cosf(a), sinf(a)); }
  __syncthreads();
  int idx = blockIdx.x*256 + threadIdx.x;
  if (idx >= M_*16) return;
  int o = idx & 15;
  int z = (idx >> 4) % 20;
  int bxy = idx / 320;
  const float2* ip = in + (size_t)bxy*160 + o;
  float acc = 0.0f; int j=0;
  for (int kz=0;kz<10;++kz) {
    float2 v = ip[kz*16];
    float2 w = tw[j];
    float re = v.x*w.x - v.y*w.y;
    acc += (kz==0) ? re : 2.0f*re;
    j += z; if (j >= 20) j -= 20;
  }
  spec[idx] = acc * (1.0f/8000.0f);
}

__global__ void pwgelu_k(const float* __restrict__ spec, const float* __restrict__ h,
                         const float* __restrict__ pw, float* __restrict__ out){
  int idx = blockIdx.x*256 + threadIdx.x;
  if (idx >= M_*16) return;
  int m = idx >> 4, o = idx & 15;
  const float* hr = h + (size_t)m*16;
  float acc = spec[idx];
  #pragma unroll
  for (int i=0;i<16;++i) acc += hr[i]*pw[i*16+o];
  out[idx] = geluf(acc);
}

__global__ void ff1g_k(const float* __restrict__ h, const float* __restrict__ Wt, float* __restrict__ out){
  int idx = blockIdx.x*256 + threadIdx.x;
  if (idx >= M_*64) return;
  int m = idx >> 6, j = idx & 63;
  const float* hr = h + (size_t)m*16;
  float acc = 0.0f;
  #pragma unroll
  for (int i=0;i<16;++i) acc += hr[i]*Wt[i*64+j];
  out[idx] = geluf(acc);
}

__global__ void ffout_k(const float* __restrict__ hB, const float* __restrict__ t,
                        const float* __restrict__ Wt, float* __restrict__ h){
  int idx = blockIdx.x*256 + threadIdx.x;
  if (idx >= M_*16) return;
  int m = idx >> 4, o = idx & 15;
  const float* tr = t + (size_t)m*64;
  float acc = hB[idx];
  #pragma unroll
  for (int j=0;j<64;++j) acc += tr[j]*Wt[j*16+o];
  h[idx] = acc;
}

__global__ void fc1g_k(const float* __restrict__ h, const float* __restrict__ Wt, float* __restrict__ out){
  int idx = blockIdx.x*256 + threadIdx.x;
  if (idx >= M_*128) return;
  int m = idx >> 7, j = idx & 127;
  const float* hr = h + (size_t)m*16;
  float acc = 0.0f;
  #pragma unroll
  for (int i=0;i<16;++i) acc += hr[i]*Wt[i*128+j];
  out[idx] = geluf(acc);
}

__global__ void fc2_k(const float* __restrict__ t, const float* __restrict__ Wt, float* __restrict__ out){
  int idx = blockIdx.x*256 + threadIdx.x;
  if (idx >= M_*16) return;
  int m = idx >> 4, o = idx & 15;
  const float* tr = t + (size_t)m*128;
  float acc = 0.0f;
  #pragma unroll
  for (int j=0;j<128;++j) acc += tr[j]*Wt[j*16+o];
  out[idx] = acc;
}

// ---------------- m2a + final ----------------
__global__ void m2a_k(const float* __restrict__ mf2, const int* __restrict__ mdst,
                      const int* __restrict__ asrc, const float* __restrict__ sh2,
                      const float* __restrict__ Wt, const float* __restrict__ EL,
                      const float* __restrict__ T, float* __restrict__ af){
  int e = blockIdx.x*256 + threadIdx.x;
  if (e >= E2_) return;
  const float* xr = mf2 + (size_t)mdst[e]*16;
  const float* sr = sh2 + (size_t)e*9;
  float sh[9];
  #pragma unroll
  for (int s=0;s<9;++s) sh[s] = sr[s];
  float acc = 0.0f;
  #pragma unroll
  for (int f=0;f<16;++f) {
    float xv = xr[f];
    float dot = 0.0f;
    #pragma unroll
    for (int s=0;s<9;++s) dot += sh[s]*Wt[f*9+s];
    acc += xv*dot;
  }
  float rv = lerp_tab(T, EL[e], 1, 0);
  atomicAdd(&af[asrc[e]], acc*rv);
}

__global__ void bsum_k(const float* __restrict__ af, const int* __restrict__ batch,
                       float* __restrict__ out){
  int n = blockIdx.x*256 + threadIdx.x;
  if (n >= N_) return;
  atomicAdd(&out[batch[n]], af[n]);
}

} // namespace

extern "C" void kernel_launch(void* const* d_in, const int* in_sizes, int n_in,
                              void* d_out, int out_size, void* d_ws, size_t ws_size,
                              hipStream_t stream) {
  (void)in_sizes; (void)n_in; (void)out_size; (void)ws_size;
  const float* pos   = (const float*)d_in[0];
  const float* cell  = (const float*)d_in[1];
  const int*   an    = (const int*)d_in[2];
  const int*   batch = (const int*)d_in[3];
  const int*   esrc  = (const int*)d_in[4];
  const int*   edst  = (const int*)d_in[5];
  const int*   asrc  = (const int*)d_in[6];
  const int*   mdst  = (const int*)d_in[7];
  const float* emb   = (const float*)d_in[8];
  const float* g0_W  = (const float*)d_in[9];
  const float* g0_Wsc= (const float*)d_in[10];
  const float* g0_m1 = (const float*)d_in[11];
  const float* g0_m2 = (const float*)d_in[12];
  const float* g0_m3 = (const float*)d_in[13];
  const float* g12_W = (const float*)d_in[14];
  const float* g12_Wsc=(const float*)d_in[15];
  const float* g12_m1= (const float*)d_in[16];
  const float* g12_m2= (const float*)d_in[17];
  const float* g12_m3= (const float*)d_in[18];
  const float* a2m_W = (const float*)d_in[19];
  const float* a2m_m1= (const float*)d_in[20];
  const float* a2m_m2= (const float*)d_in[21];
  const float* a2m_m3= (const float*)d_in[22];
  const float* m2a_W = (const float*)d_in[23];
  const float* m2a_m1= (const float*)d_in[24];
  const float* m2a_m2= (const float*)d_in[25];
  const float* m2a_m3= (const float*)d_in[26];
  const float* fc0_W = (const float*)d_in[27];
  const float* fc0_b = (const float*)d_in[28];
  const float* sw_r  = (const float*)d_in[29];
  const float* sw_i  = (const float*)d_in[30];
  const float* pw    = (const float*)d_in[31];
  const float* ff1   = (const float*)d_in[32];
  const float* ff2   = (const float*)d_in[33];
  const float* fc1   = (const float*)d_in[34];
  const float* fc2   = (const float*)d_in[35];
  float* out = (float*)d_out;

  float* Wp = (float*)d_ws;
  size_t off = 0;
  auto alloc = [&](size_t n){ float* p = Wp + off; off += n; return p; };
  float* meshpos = alloc((size_t)M_*3);
  float* she   = alloc((size_t)E_*9);
  float* ELe   = alloc((size_t)E_);
  float* sh2   = alloc((size_t)E2_*9);
  float* EL2   = alloc((size_t)E2_);
  float* x16   = alloc((size_t)N_*16);
  float* xatom = alloc((size_t)N_*144);
  float* xact  = alloc((size_t)N_*144);
  float* rh1   = alloc((size_t)M_*128);          // FNO ff/fc scratch
  float* Wt    = alloc((size_t)144*1296);        // reshaped expanded weights
  float* Yg    = alloc((size_t)N_*1296);         // per-atom Y
  float* mf    = alloc((size_t)M_*32);
  float* hbuf  = alloc((size_t)M_*16);
  float* htmp  = alloc((size_t)M_*16);
  float* htmp2 = alloc((size_t)M_*16);
  float2* cA   = (float2*)alloc(1024000);
  float2* cB   = (float2*)alloc(1024000);
  float* af    = alloc((size_t)N_);
  float* Es    = alloc((size_t)NT_*64);
  float* H1g   = alloc((size_t)5*NT_*128);
  float* H2g   = alloc((size_t)5*NT_*128);
  float* T0    = alloc((size_t)NT_*144);
  float* T1    = alloc((size_t)NT_*144);
  float* T2    = alloc((size_t)NT_*144);
  float* T3    = alloc((size_t)NT_*32);
  float* T4    = alloc((size_t)NT_*1);

  auto g1 = [](int n){ return dim3((unsigned)((n+255)/256)); };
  auto gg = [](int Mr, int Nc){ return dim3((unsigned)((Nc+63)/64), (unsigned)((Mr+63)/64)); };

  // zero accumulators
  zero_k<<<g1(8), 256, 0, stream>>>(out, 8);
  zero_k<<<g1(N_), 256, 0, stream>>>(af, N_);
  zero_k<<<g1(M_*32), 256, 0, stream>>>(mf, M_*32);

  // geometry
  meshpos_k<<<g1(M_), 256, 0, stream>>>(cell, meshpos);
  edge_geom2_k<<<g1(E_), 256, 0, stream>>>(pos, esrc, pos, edst, she, ELe, E_);
  edge_geom2_k<<<g1(E2_), 256, 0, stream>>>(meshpos, mdst, pos, asrc, sh2, EL2, E2_);
  gather_emb_k<<<g1(N_*16), 256, 0, stream>>>(emb, an, x16);

  // ---- radial tables via 3 batched GEMMs ----
  {
    es_k<<<g1(NT_*64), 256, 0, stream>>>(Es);
    BG l1, l2, l3;
    const float* m1s[5] = {g0_m1, g12_m1, g12_m1+(size_t)64*128, a2m_m1, m2a_m1};
    const float* m2s[5] = {g0_m2, g12_m2, g12_m2+(size_t)128*128, a2m_m2, m2a_m2};
    const float* m3s[5] = {g0_m3, g12_m3, g12_m3+(size_t)128*144, a2m_m3, m2a_m3};
    float* Ts[5] = {T0, T1, T2, T3, T4};
    int NOs[5] = {144, 144, 144, 32, 1};
    for (int c = 0; c < 5; ++c) {
      l1.A[c] = Es;                     l1.B[c] = m1s[c]; l1.C[c] = H1g + (size_t)c*NT_*128; l1.Nc[c] = 128;
      l2.A[c] = H1g + (size_t)c*NT_*128; l2.B[c] = m2s[c]; l2.C[c] = H2g + (size_t)c*NT_*128; l2.Nc[c] = 128;
      l3.A[c] = H2g + (size_t)c*NT_*128; l3.B[c] = m3s[c]; l3.C[c] = Ts[c];                   l3.Nc[c] = NOs[c];
    }
    l1.K = 64; l2.K = 128; l3.K = 128;
    bgemm_k<1><<<dim3(2, NT_/64, 5), 256, 0, stream>>>(l1);
    bgemm_k<1><<<dim3(2, NT_/64, 5), 256, 0, stream>>>(l2);
    bgemm_k<0><<<dim3(3, NT_/64, 5), 256, 0, stream>>>(l3);
  }

  // ---- g0 ----
  wreshape_k<144><<<g1(16*9*144), 256, 0, stream>>>(g0_W, Wt, 16);
  gemm_k<<<gg(N_,1296), 256, 0, stream>>>(x16, Wt, Yg, N_, 16, 1296);
  wscinit_k<<<g1(N_*144), 256, 0, stream>>>(x16, g0_Wsc, xatom, N_, 16, 144);
  econtract_k<144><<<g1(E_*144), 256, 0, stream>>>(Yg, esrc, edst, she, ELe, T0, xatom, E_);

  // ---- g12 x2 ----
  for (int i = 0; i < 2; ++i) {
    normact_k<<<g1(N_*16), 256, 0, stream>>>(xatom, xact);
    wreshape_k<144><<<g1(144*9*144), 256, 0, stream>>>(g12_W + (size_t)i*1296*144, Wt, 144);
    gemm_k<<<gg(N_,1296), 256, 0, stream>>>(xact, Wt, Yg, N_, 144, 1296);
    wscinit_k<<<g1(N_*144), 256, 0, stream>>>(xact, g12_Wsc + (size_t)i*144*144, xatom, N_, 144, 144);
    econtract_k<144><<<g1(E_*144), 256, 0, stream>>>(Yg, esrc, edst, she, ELe, (i==0)?T1:T2, xatom, E_);
  }

  // ---- a2m ----
  wreshape_k<32><<<g1(144*9*32), 256, 0, stream>>>(a2m_W, Wt, 144);
  gemm_k<<<gg(N_,288), 256, 0, stream>>>(xatom, Wt, Yg, N_, 144, 288);
  econtract_k<32><<<g1(E2_*32), 256, 0, stream>>>(Yg, asrc, mdst, sh2, EL2, T3, mf, E2_);
  sigabs_k<<<g1(M_*32), 256, 0, stream>>>(mf, M_*32);

  // ---- FNO ----
  fc0_k<<<g1(M_*16), 256, 0, stream>>>(mf, fc0_W, fc0_b, hbuf);
  for (int l = 0; l < 3; ++l) {
    zfwd_k<<<g1(512000), 256, 0, stream>>>(hbuf, cA);
    cdft_k<<<g1(512000), 256, 0, stream>>>(cA, cB, 160, 512000, -1.0f);  // y fwd
    cdft_k<<<g1(512000), 256, 0, stream>>>(cB, cA, 3200, 512000, -1.0f); // x fwd
    mix_k<<<g1(512000), 256, 0, stream>>>(cA, cB, sw_r + (size_t)l*1024000, sw_i + (size_t)l*1024000);
    cdft_k<<<g1(512000), 256, 0, stream>>>(cB, cA, 3200, 512000, 1.0f);  // x inv
    cdft_k<<<g1(512000), 256, 0, stream>>>(cA, cB, 160, 512000, 1.0f);   // y inv
    zinv_k<<<g1(M_*16), 256, 0, stream>>>(cB, htmp);
    pwgelu_k<<<g1(M_*16), 256, 0, stream>>>(htmp, hbuf, pw + (size_t)l*256, htmp2);
    ff1g_k<<<g1(M_*64), 256, 0, stream>>>(htmp2, ff1 + (size_t)l*1024, rh1);
    ffout_k<<<g1(M_*16), 256, 0, stream>>>(htmp2, rh1, ff2 + (size_t)l*1024, hbuf);
  }
  fc1g_k<<<g1(M_*128), 256, 0, stream>>>(hbuf, fc1, rh1);
  fc2_k<<<g1(M_*16), 256, 0, stream>>>(rh1, fc2, htmp);

  // ---- m2a + batch reduce ----
  m2a_k<<<g1(E2_), 256, 0, stream>>>(htmp, mdst, asrc, sh2, m2a_W, EL2, T4, af);
  bsum_k<<<g1(N_), 256, 0, stream>>>(af, batch, out);
}

// Round 5
// 703.925 us; speedup vs baseline: 2.5753x; 1.1440x over previous
//
#include <hip/hip_runtime.h>
#include <math.h>

#define DEVI __device__ __forceinline__

namespace {

constexpr int N_  = 2048;
constexpr int E_  = 32768;
constexpr int E2_ = 65536;
constexpr int M_  = 64000;   // 8 * 20^3
constexpr int NT_ = 4096;    // radial table resolution
constexpr float TMAX_ = 5.5f;
constexpr float TH_ = TMAX_ / NT_;

DEVI float sigm(float x)  { return 1.0f/(1.0f+expf(-x)); }
DEVI float geluf(float x) {
  float t = tanhf(0.7978845608028654f*(x + 0.044715f*x*x*x));
  return 0.5f*x*(1.0f+t);
}

// ---------------- utility ----------------
__global__ void zero_k(float* __restrict__ p, int n){
  int i = blockIdx.x*256 + threadIdx.x;
  if (i < n) p[i] = 0.0f;
}

__global__ void meshpos_k(const float* __restrict__ cell, float* __restrict__ mp){
  int m = blockIdx.x*256 + threadIdx.x;
  if (m >= M_) return;
  int b = m/8000, r = m%8000;
  float fx = (float)(r/400)    * 0.05f;
  float fy = (float)((r/20)%20)* 0.05f;
  float fz = (float)(r%20)     * 0.05f;
  const float* c = cell + b*9;
  mp[(size_t)m*3+0] = fx*c[0] + fy*c[3] + fz*c[6];
  mp[(size_t)m*3+1] = fx*c[1] + fy*c[4] + fz*c[7];
  mp[(size_t)m*3+2] = fx*c[2] + fy*c[5] + fz*c[8];
}

// edge geometry: ev = P[pi[e]] - Q[qi[e]]; writes sh (9) and el (1)
__global__ void edge_geom2_k(const float* __restrict__ Ppos, const int* __restrict__ pi,
                             const float* __restrict__ Qpos, const int* __restrict__ qi,
                             float* __restrict__ sh, float* __restrict__ el_out, int nE){
  int e = blockIdx.x*256 + threadIdx.x;
  if (e >= nE) return;
  int a = pi[e], b = qi[e];
  float ex = Ppos[(size_t)a*3+0] - Qpos[(size_t)b*3+0];
  float ey = Ppos[(size_t)a*3+1] - Qpos[(size_t)b*3+1];
  float ez = Ppos[(size_t)a*3+2] - Qpos[(size_t)b*3+2];
  float el = sqrtf(ex*ex+ey*ey+ez*ez) + 1e-8f;
  el_out[e] = el;
  float x = ex/el, y = ey/el, z = ez/el;
  float* s = sh + (size_t)e*9;
  s[0] = 0.28209479177387814f;
  s[1] = 0.4886025119029199f*y;
  s[2] = 0.4886025119029199f*z;
  s[3] = 0.4886025119029199f*x;
  s[4] = 1.0925484305920792f*x*y;
  s[5] = 1.0925484305920792f*y*z;
  s[6] = 0.31539156525252005f*(3.0f*z*z-1.0f);
  s[7] = 1.0925484305920792f*x*z;
  s[8] = 0.5462742152960396f*(x*x-y*y);
}

__global__ void gather_emb_k(const float* __restrict__ emb, const int* __restrict__ an,
                             float* __restrict__ x16){
  int idx = blockIdx.x*256 + threadIdx.x;
  if (idx >= N_*16) return;
  int n = idx >> 4, f = idx & 15;
  x16[idx] = emb[(size_t)an[n]*16 + f];
}

// ---------------- radial tables ----------------
__global__ void es_k(float* __restrict__ Es){
  int idx = blockIdx.x*256 + threadIdx.x;
  if (idx >= NT_*64) return;
  int r = idx >> 6, k = idx & 63;
  const float step = 5.0f/63.0f;
  float d = (r*TH_ - k*step)/step;
  Es[idx] = expf(-d*d)*(8.0f/1.12f);
}

DEVI float lerp_tab(const float* __restrict__ T, float el, int O, int o){
  float u = el * (1.0f/TH_);
  u = fminf(u, (float)(NT_-1));
  int i = (int)u; if (i > NT_-2) i = NT_-2;
  float f = u - (float)i;
  float t0 = T[(size_t)i*O + o];
  float t1 = T[(size_t)(i+1)*O + o];
  return t0 + f*(t1 - t0);
}

// ---------------- tiled GEMM ----------------
#define BM 64
#define BN 64
#define BK 16

struct BG {
  const float* A[5]; const float* B[5]; float* C[5];
  int K; int Nc[5];
};
template<int ACT>
__global__ __launch_bounds__(256) void bgemm_k(BG args){
  int chain = blockIdx.z;
  const float* A = args.A[chain];
  const float* Bm = args.B[chain];
  float* C = args.C[chain];
  int K = args.K, Nc = args.Nc[chain];
  int row0 = blockIdx.y*BM, col0 = blockIdx.x*BN;
  if (col0 >= Nc) return;
  __shared__ float As[BK][BM+4];
  __shared__ float Bs[BK][BN+4];
  int tid = threadIdx.x;
  int tx = tid & 15, ty = tid >> 4;
  float acc[4][4] = {};
  for (int k0 = 0; k0 < K; k0 += BK) {
    { int kk = tid & 15; int mloc = tid >> 4;
      int gk = k0 + kk;
      for (int p = 0; p < 4; ++p) {
        int m = mloc + p*16; int gm = row0 + m;
        As[kk][m] = A[(size_t)gm*K + gk];
      } }
    { int nn = tid & 63; int kl = tid >> 6;
      for (int p = 0; p < 4; ++p) {
        int kk = kl + p*4; int gk = k0 + kk; int gn = col0 + nn;
        Bs[kk][nn] = (gn < Nc) ? Bm[(size_t)gk*Nc + gn] : 0.0f;
      } }
    __syncthreads();
    #pragma unroll
    for (int kk = 0; kk < BK; ++kk) {
      float a[4], b[4];
      #pragma unroll
      for (int i=0;i<4;++i) a[i] = As[kk][ty*4+i];
      #pragma unroll
      for (int j=0;j<4;++j) b[j] = Bs[kk][tx*4+j];
      #pragma unroll
      for (int i=0;i<4;++i)
        #pragma unroll
        for (int j=0;j<4;++j) acc[i][j] += a[i]*b[j];
    }
    __syncthreads();
  }
  for (int i=0;i<4;++i) {
    int gm = row0 + ty*4+i;
    for (int j=0;j<4;++j) {
      int gn = col0 + tx*4+j; if (gn >= Nc) continue;
      float v = acc[i][j];
      if (ACT==1) v = v*sigm(v);
      C[(size_t)gm*Nc + gn] = v;
    }
  }
}

__global__ __launch_bounds__(256) void gemm_k(const float* __restrict__ A, const float* __restrict__ B,
                      float* __restrict__ C, int Mr, int K, int Nc){
  __shared__ float As[BK][BM+4];
  __shared__ float Bs[BK][BN+4];
  int tid = threadIdx.x;
  int row0 = blockIdx.y*BM, col0 = blockIdx.x*BN;
  int tx = tid & 15, ty = tid >> 4;
  float acc[4][4] = {};
  for (int k0 = 0; k0 < K; k0 += BK) {
    { int kk = tid & 15; int mloc = tid >> 4;
      int gk = k0 + kk;
      for (int p = 0; p < 4; ++p) {
        int m = mloc + p*16; int gm = row0 + m;
        As[kk][m] = (gm < Mr && gk < K) ? A[(size_t)gm*K + gk] : 0.0f;
      } }
    { int nn = tid & 63; int kl = tid >> 6;
      for (int p = 0; p < 4; ++p) {
        int kk = kl + p*4; int gk = k0 + kk; int gn = col0 + nn;
        Bs[kk][nn] = (gk < K && gn < Nc) ? B[(size_t)gk*Nc + gn] : 0.0f;
      } }
    __syncthreads();
    #pragma unroll
    for (int kk = 0; kk < BK; ++kk) {
      float a[4], b[4];
      #pragma unroll
      for (int i=0;i<4;++i) a[i] = As[kk][ty*4+i];
      #pragma unroll
      for (int j=0;j<4;++j) b[j] = Bs[kk][tx*4+j];
      #pragma unroll
      for (int i=0;i<4;++i)
        #pragma unroll
        for (int j=0;j<4;++j) acc[i][j] += a[i]*b[j];
    }
    __syncthreads();
  }
  for (int i=0;i<4;++i) {
    int gm = row0 + ty*4+i; if (gm >= Mr) continue;
    for (int j=0;j<4;++j) {
      int gn = col0 + tx*4+j; if (gn >= Nc) continue;
      C[(size_t)gm*Nc + gn] = acc[i][j];
    }
  }
}

// Wt[f*(9*O) + s*O + o] = W[(f*9+s)*O + o]
template<int O>
__global__ void wreshape_k(const float* __restrict__ W, float* __restrict__ Wt, int F){
  int idx = blockIdx.x*256 + threadIdx.x;
  int total = F*9*O;
  if (idx >= total) return;
  int o = idx % O; int s = (idx / O) % 9; int f = idx / (9*O);
  Wt[idx] = W[(size_t)(f*9+s)*O + o];
}

// per-edge: out[dst[e],o] += (sum_s sh[e,s]*Y[src[e], s*O+o]) * lerp(T, el[e], o)
template<int O>
__global__ void econtract_k(const float* __restrict__ Y, const int* __restrict__ src,
                            const int* __restrict__ dst, const float* __restrict__ SH,
                            const float* __restrict__ EL, const float* __restrict__ T,
                            float* __restrict__ out, int nE){
  int idx = blockIdx.x*256 + threadIdx.x;
  if (idx >= nE*O) return;
  int e = idx / O, o = idx - e*O;
  const float* sr = SH + (size_t)e*9;
  const float* yr = Y + (size_t)src[e]*(9*O) + o;
  float acc = 0.0f;
  #pragma unroll
  for (int s = 0; s < 9; ++s) acc += sr[s] * yr[s*O];
  float rv = lerp_tab(T, EL[e], O, o);
  atomicAdd(&out[(size_t)dst[e]*O + o], acc * rv);
}

// ---------------- GCN pieces ----------------
__global__ void normact_k(const float* __restrict__ x, float* __restrict__ y){
  int idx = blockIdx.x*256 + threadIdx.x;
  if (idx >= N_*16) return;
  int n = idx >> 4, r = idx & 15;
  const float* xr = x + (size_t)n*144;
  float* yr = y + (size_t)n*144;
  float s = xr[r];
  yr[r] = s * sigm(fabsf(s));
  float v0 = xr[16+r*3], v1 = xr[16+r*3+1], v2 = xr[16+r*3+2];
  float gv = sigm(sqrtf(v0*v0+v1*v1+v2*v2));
  yr[16+r*3]=v0*gv; yr[16+r*3+1]=v1*gv; yr[16+r*3+2]=v2*gv;
  float t0=xr[64+r*5],t1=xr[64+r*5+1],t2=xr[64+r*5+2],t3=xr[64+r*5+3],t4=xr[64+r*5+4];
  float gt = sigm(sqrtf(t0*t0+t1*t1+t2*t2+t3*t3+t4*t4));
  yr[64+r*5]=t0*gt; yr[64+r*5+1]=t1*gt; yr[64+r*5+2]=t2*gt; yr[64+r*5+3]=t3*gt; yr[64+r*5+4]=t4*gt;
}

__global__ void sigabs_k(float* __restrict__ x, int n){
  int i = blockIdx.x*256 + threadIdx.x;
  if (i < n) { float v = x[i]; x[i] = v * sigm(fabsf(v)); }
}

// ---------------- FNO ----------------
__global__ void fc0_k(const float* __restrict__ mf, const float* __restrict__ Wt,
                      const float* __restrict__ bb, float* __restrict__ h){
  int idx = blockIdx.x*256 + threadIdx.x;
  if (idx >= M_*16) return;
  int m = idx >> 4, o = idx & 15;
  int r = m % 8000;
  float fx = (float)(r/400)*0.05f, fy = (float)((r/20)%20)*0.05f, fz = (float)(r%20)*0.05f;
  const float* mfr = mf + (size_t)m*32;
  float acc = bb[o];
  #pragma unroll
  for (int j=0;j<32;++j) acc += mfr[j]*Wt[j*16+o];
  acc += fx*Wt[32*16+o] + fy*Wt[33*16+o] + fz*Wt[34*16+o];
  h[idx] = acc;
}

__global__ void zfwd_k(const float* __restrict__ h, float2* __restrict__ out){
  __shared__ float2 tw[20];
  if (threadIdx.x < 20) { float a = -6.283185307179586f*threadIdx.x/20.0f; tw[threadIdx.x] = make_float2(cosf(a), sinf(a)); }
  __syncthreads();
  int idx = blockIdx.x*256 + threadIdx.x;
  if (idx >= 512000) return;
  int i = idx & 15;
  int kz = (idx >> 4) % 10;
  int bxy = idx / 160;
  const float* hp = h + (size_t)bxy*320 + i;
  float sr=0.0f, si=0.0f; int j=0;
  for (int z=0; z<20; ++z) {
    float v = hp[z*16];
    float2 t = tw[j];
    sr += v*t.x; si += v*t.y;
    j += kz; if (j >= 20) j -= 20;
  }
  out[idx] = make_float2(sr, si);
}

__global__ void cdft_k(const float2* __restrict__ in, float2* __restrict__ out,
                       int innerSz, int total, float sign){
  __shared__ float2 tw[20];
  if (threadIdx.x < 20) { float a = sign*6.283185307179586f*threadIdx.x/20.0f; tw[threadIdx.x] = make_float2(cosf(a), sinf(a)); }
  __syncthreads();
  int idx = blockIdx.x*256 + threadIdx.x;
  if (idx >= total) return;
  int inner = idx % innerSz;
  int ko = (idx / innerSz) % 20;
  int outer = idx / (innerSz*20);
  const float2* ip = in + (size_t)outer*20*innerSz + inner;
  float sr=0.0f, si=0.0f; int j=0;
  for (int t=0;t<20;++t) {
    float2 v = ip[(size_t)t*innerSz];
    float2 w = tw[j];
    sr += v.x*w.x - v.y*w.y;
    si += v.x*w.y + v.y*w.x;
    j += ko; if (j >= 20) j -= 20;
  }
  out[idx] = make_float2(sr, si);
}

__global__ void mix_k(const float2* __restrict__ in, float2* __restrict__ out,
                      const float* __restrict__ wr, const float* __restrict__ wi){
  int idx = blockIdx.x*256 + threadIdx.x;
  if (idx >= 512000) return;
  int o = idx & 15;
  int kz = (idx >> 4) % 10;
  int t = idx / 160;                  // (b*20+kx)*20+ky
  int ky = t % 20, kx = (t/20) % 20;
  int c = (kx>=10 ? 1 : 0) + (ky>=10 ? 2 : 0);
  int xx = kx % 10, yy = ky % 10;
  size_t wbase = ((size_t)(c*16)*16 + o)*1000 + xx*100 + yy*10 + kz;
  size_t ibase = (size_t)t*160 + kz*16;
  float sr=0.0f, si=0.0f;
  #pragma unroll
  for (int i=0;i<16;++i) {
    float2 a = in[ibase + i];
    float wrv = wr[wbase + (size_t)i*16000];
    float wiv = wi[wbase + (size_t)i*16000];
    sr += a.x*wrv - a.y*wiv;
    si += a.x*wiv + a.y*wrv;
  }
  out[idx] = make_float2(sr, si);
}

__global__ void zinv_k(const float2* __restrict__ in, float* __restrict__ spec){
  __shared__ float2 tw[20];
  if (threadIdx.x < 20) { float a = 6.283185307179586f*threadIdx.x/20.0f; tw[threadIdx.x] = make_float2(cosf(a), sinf(a)); }
  __syncthreads();
  int idx = blockIdx.x*256 + threadIdx.x;
  if (idx >= M_*16) return;
  int o = idx & 15;
  int z = (idx >> 4) % 20;
  int bxy = idx / 320;
  const float2* ip = in + (size_t)bxy*160 + o;
  float acc = 0.0f; int j=0;
  for (int kz=0;kz<10;++kz) {
    float2 v = ip[kz*16];
    float2 w = tw[j];
    float re = v.x*w.x - v.y*w.y;
    acc += (kz==0) ? re : 2.0f*re;
    j += z; if (j >= 20) j -= 20;
  }
  spec[idx] = acc * (1.0f/8000.0f);
}

// fused FNO tail: h2 = gelu(spec + h@pw); hout = h2 + gelu(h2@ff1)@ff2
__global__ __launch_bounds__(256) void ffn_k(const float* __restrict__ spec, const float* __restrict__ h,
                      const float* __restrict__ pw, const float* __restrict__ ff1,
                      const float* __restrict__ ff2, float* __restrict__ hout){
  __shared__ float spw[256];
  __shared__ float sf1[1024];
  __shared__ float sf2[1024];
  int tid = threadIdx.x;
  spw[tid] = pw[tid];
  for (int t = tid; t < 1024; t += 256) { sf1[t] = ff1[t]; sf2[t] = ff2[t]; }
  __syncthreads();
  int m = blockIdx.x*256 + tid;
  if (m >= M_) return;
  const float* hr = h + (size_t)m*16;
  const float* sp = spec + (size_t)m*16;
  float hl[16], h2[16];
  #pragma unroll
  for (int i=0;i<16;++i) hl[i] = hr[i];
  #pragma unroll
  for (int o=0;o<16;++o){
    float acc = sp[o];
    #pragma unroll
    for (int i=0;i<16;++i) acc += hl[i]*spw[i*16+o];
    h2[o] = geluf(acc);
  }
  float outv[16];
  #pragma unroll
  for (int o=0;o<16;++o) outv[o] = h2[o];
  for (int k=0;k<64;++k){
    float acc = 0.0f;
    #pragma unroll
    for (int i=0;i<16;++i) acc += h2[i]*sf1[i*64+k];
    float tk = geluf(acc);
    #pragma unroll
    for (int o=0;o<16;++o) outv[o] += tk*sf2[k*16+o];
  }
  float* ho = hout + (size_t)m*16;
  #pragma unroll
  for (int o=0;o<16;++o) ho[o] = outv[o];
}

// fused final projection: out = gelu(h@fc1)@fc2
__global__ __launch_bounds__(256) void fctail_k(const float* __restrict__ h, const float* __restrict__ fc1,
                         const float* __restrict__ fc2, float* __restrict__ outm){
  __shared__ float s1[2048];
  __shared__ float s2[2048];
  int tid = threadIdx.x;
  for (int t = tid; t < 2048; t += 256){ s1[t] = fc1[t]; s2[t] = fc2[t]; }
  __syncthreads();
  int m = blockIdx.x*256 + tid;
  if (m >= M_) return;
  const float* hr = h + (size_t)m*16;
  float hl[16];
  #pragma unroll
  for (int i=0;i<16;++i) hl[i] = hr[i];
  float outv[16] = {};
  for (int k=0;k<128;++k){
    float acc = 0.0f;
    #pragma unroll
    for (int i=0;i<16;++i) acc += hl[i]*s1[i*128+k];
    float tk = geluf(acc);
    #pragma unroll
    for (int o=0;o<16;++o) outv[o] += tk*s2[k*16+o];
  }
  float* po = outm + (size_t)m*16;
  #pragma unroll
  for (int o=0;o<16;++o) po[o] = outv[o];
}

// ---------------- m2a + final ----------------
__global__ void m2a_k(const float* __restrict__ mf2, const int* __restrict__ mdst,
                      const int* __restrict__ asrc, const float* __restrict__ sh2,
                      const float* __restrict__ Wt, const float* __restrict__ EL,
                      const float* __restrict__ T, float* __restrict__ af){
  int e = blockIdx.x*256 + threadIdx.x;
  if (e >= E2_) return;
  const float* xr = mf2 + (size_t)mdst[e]*16;
  const float* sr = sh2 + (size_t)e*9;
  float sh[9];
  #pragma unroll
  for (int s=0;s<9;++s) sh[s] = sr[s];
  float acc = 0.0f;
  #pragma unroll
  for (int f=0;f<16;++f) {
    float xv = xr[f];
    float dot = 0.0f;
    #pragma unroll
    for (int s=0;s<9;++s) dot += sh[s]*Wt[f*9+s];
    acc += xv*dot;
  }
  float rv = lerp_tab(T, EL[e], 1, 0);
  atomicAdd(&af[asrc[e]], acc*rv);
}

__global__ void bsum_k(const float* __restrict__ af, const int* __restrict__ batch,
                       float* __restrict__ out){
  int n = blockIdx.x*256 + threadIdx.x;
  if (n >= N_) return;
  atomicAdd(&out[batch[n]], af[n]);
}

} // namespace

extern "C" void kernel_launch(void* const* d_in, const int* in_sizes, int n_in,
                              void* d_out, int out_size, void* d_ws, size_t ws_size,
                              hipStream_t stream) {
  (void)in_sizes; (void)n_in; (void)out_size; (void)ws_size;
  const float* pos   = (const float*)d_in[0];
  const float* cell  = (const float*)d_in[1];
  const int*   an    = (const int*)d_in[2];
  const int*   batch = (const int*)d_in[3];
  const int*   esrc  = (const int*)d_in[4];
  const int*   edst  = (const int*)d_in[5];
  const int*   asrc  = (const int*)d_in[6];
  const int*   mdst  = (const int*)d_in[7];
  const float* emb   = (const float*)d_in[8];
  const float* g0_W  = (const float*)d_in[9];
  const float* g0_Wsc= (const float*)d_in[10];
  const float* g0_m1 = (const float*)d_in[11];
  const float* g0_m2 = (const float*)d_in[12];
  const float* g0_m3 = (const float*)d_in[13];
  const float* g12_W = (const float*)d_in[14];
  const float* g12_Wsc=(const float*)d_in[15];
  const float* g12_m1= (const float*)d_in[16];
  const float* g12_m2= (const float*)d_in[17];
  const float* g12_m3= (const float*)d_in[18];
  const float* a2m_W = (const float*)d_in[19];
  const float* a2m_m1= (const float*)d_in[20];
  const float* a2m_m2= (const float*)d_in[21];
  const float* a2m_m3= (const float*)d_in[22];
  const float* m2a_W = (const float*)d_in[23];
  const float* m2a_m1= (const float*)d_in[24];
  const float* m2a_m2= (const float*)d_in[25];
  const float* m2a_m3= (const float*)d_in[26];
  const float* fc0_W = (const float*)d_in[27];
  const float* fc0_b = (const float*)d_in[28];
  const float* sw_r  = (const float*)d_in[29];
  const float* sw_i  = (const float*)d_in[30];
  const float* pw    = (const float*)d_in[31];
  const float* ff1   = (const float*)d_in[32];
  const float* ff2   = (const float*)d_in[33];
  const float* fc1   = (const float*)d_in[34];
  const float* fc2   = (const float*)d_in[35];
  float* out = (float*)d_out;

  float* Wp = (float*)d_ws;
  size_t off = 0;
  auto alloc = [&](size_t n){ float* p = Wp + off; off += n; return p; };
  float* meshpos = alloc((size_t)M_*3);
  float* she   = alloc((size_t)E_*9);
  float* ELe   = alloc((size_t)E_);
  float* sh2   = alloc((size_t)E2_*9);
  float* EL2   = alloc((size_t)E2_);
  float* x16   = alloc((size_t)N_*16);
  float* xatom = alloc((size_t)N_*144);
  float* xact  = alloc((size_t)N_*144);
  float* Wt    = alloc((size_t)144*1296);        // reshaped expanded weights
  float* Yg    = alloc((size_t)N_*1296);         // per-atom Y
  float* mf    = alloc((size_t)M_*32);
  float* hbuf  = alloc((size_t)M_*16);
  float* htmp  = alloc((size_t)M_*16);
  float2* cA   = (float2*)alloc(1024000);
  float2* cB   = (float2*)alloc(1024000);
  float* af    = alloc((size_t)N_);
  float* Es    = alloc((size_t)NT_*64);
  float* H1g   = alloc((size_t)5*NT_*128);
  float* H2g   = alloc((size_t)5*NT_*128);
  float* T0    = alloc((size_t)NT_*144);
  float* T1    = alloc((size_t)NT_*144);
  float* T2    = alloc((size_t)NT_*144);
  float* T3    = alloc((size_t)NT_*32);
  float* T4    = alloc((size_t)NT_*1);

  auto g1 = [](int n){ return dim3((unsigned)((n+255)/256)); };
  auto gg = [](int Mr, int Nc){ return dim3((unsigned)((Nc+63)/64), (unsigned)((Mr+63)/64)); };

  // zero accumulators
  zero_k<<<g1(8), 256, 0, stream>>>(out, 8);
  zero_k<<<g1(N_), 256, 0, stream>>>(af, N_);
  zero_k<<<g1(M_*32), 256, 0, stream>>>(mf, M_*32);

  // geometry
  meshpos_k<<<g1(M_), 256, 0, stream>>>(cell, meshpos);
  edge_geom2_k<<<g1(E_), 256, 0, stream>>>(pos, esrc, pos, edst, she, ELe, E_);
  edge_geom2_k<<<g1(E2_), 256, 0, stream>>>(meshpos, mdst, pos, asrc, sh2, EL2, E2_);
  gather_emb_k<<<g1(N_*16), 256, 0, stream>>>(emb, an, x16);

  // ---- radial tables via 3 batched GEMMs ----
  {
    es_k<<<g1(NT_*64), 256, 0, stream>>>(Es);
    BG l1, l2, l3;
    const float* m1s[5] = {g0_m1, g12_m1, g12_m1+(size_t)64*128, a2m_m1, m2a_m1};
    const float* m2s[5] = {g0_m2, g12_m2, g12_m2+(size_t)128*128, a2m_m2, m2a_m2};
    const float* m3s[5] = {g0_m3, g12_m3, g12_m3+(size_t)128*144, a2m_m3, m2a_m3};
    float* Ts[5] = {T0, T1, T2, T3, T4};
    int NOs[5] = {144, 144, 144, 32, 1};
    for (int c = 0; c < 5; ++c) {
      l1.A[c] = Es;                      l1.B[c] = m1s[c]; l1.C[c] = H1g + (size_t)c*NT_*128; l1.Nc[c] = 128;
      l2.A[c] = H1g + (size_t)c*NT_*128; l2.B[c] = m2s[c]; l2.C[c] = H2g + (size_t)c*NT_*128; l2.Nc[c] = 128;
      l3.A[c] = H2g + (size_t)c*NT_*128; l3.B[c] = m3s[c]; l3.C[c] = Ts[c];                   l3.Nc[c] = NOs[c];
    }
    l1.K = 64; l2.K = 128; l3.K = 128;
    bgemm_k<1><<<dim3(2, NT_/64, 5), 256, 0, stream>>>(l1);
    bgemm_k<1><<<dim3(2, NT_/64, 5), 256, 0, stream>>>(l2);
    bgemm_k<0><<<dim3(3, NT_/64, 5), 256, 0, stream>>>(l3);
  }

  // ---- g0 ----
  wreshape_k<144><<<g1(16*9*144), 256, 0, stream>>>(g0_W, Wt, 16);
  gemm_k<<<gg(N_,1296), 256, 0, stream>>>(x16, Wt, Yg, N_, 16, 1296);
  gemm_k<<<gg(N_,144), 256, 0, stream>>>(x16, g0_Wsc, xatom, N_, 16, 144);
  econtract_k<144><<<g1(E_*144), 256, 0, stream>>>(Yg, esrc, edst, she, ELe, T0, xatom, E_);

  // ---- g12 x2 ----
  for (int i = 0; i < 2; ++i) {
    normact_k<<<g1(N_*16), 256, 0, stream>>>(xatom, xact);
    wreshape_k<144><<<g1(144*9*144), 256, 0, stream>>>(g12_W + (size_t)i*1296*144, Wt, 144);
    gemm_k<<<gg(N_,1296), 256, 0, stream>>>(xact, Wt, Yg, N_, 144, 1296);
    gemm_k<<<gg(N_,144), 256, 0, stream>>>(xact, g12_Wsc + (size_t)i*144*144, xatom, N_, 144, 144);
    econtract_k<144><<<g1(E_*144), 256, 0, stream>>>(Yg, esrc, edst, she, ELe, (i==0)?T1:T2, xatom, E_);
  }

  // ---- a2m ----
  wreshape_k<32><<<g1(144*9*32), 256, 0, stream>>>(a2m_W, Wt, 144);
  gemm_k<<<gg(N_,288), 256, 0, stream>>>(xatom, Wt, Yg, N_, 144, 288);
  econtract_k<32><<<g1(E2_*32), 256, 0, stream>>>(Yg, asrc, mdst, sh2, EL2, T3, mf, E2_);
  sigabs_k<<<g1(M_*32), 256, 0, stream>>>(mf, M_*32);

  // ---- FNO ----
  fc0_k<<<g1(M_*16), 256, 0, stream>>>(mf, fc0_W, fc0_b, hbuf);
  for (int l = 0; l < 3; ++l) {
    zfwd_k<<<g1(512000), 256, 0, stream>>>(hbuf, cA);
    cdft_k<<<g1(512000), 256, 0, stream>>>(cA, cB, 160, 512000, -1.0f);  // y fwd
    cdft_k<<<g1(512000), 256, 0, stream>>>(cB, cA, 3200, 512000, -1.0f); // x fwd
    mix_k<<<g1(512000), 256, 0, stream>>>(cA, cB, sw_r + (size_t)l*1024000, sw_i + (size_t)l*1024000);
    cdft_k<<<g1(512000), 256, 0, stream>>>(cB, cA, 3200, 512000, 1.0f);  // x inv
    cdft_k<<<g1(512000), 256, 0, stream>>>(cA, cB, 160, 512000, 1.0f);   // y inv
    zinv_k<<<g1(M_*16), 256, 0, stream>>>(cB, htmp);
    ffn_k<<<g1(M_), 256, 0, stream>>>(htmp, hbuf, pw + (size_t)l*256,
                                      ff1 + (size_t)l*1024, ff2 + (size_t)l*1024, hbuf);
  }
  fctail_k<<<g1(M_), 256, 0, stream>>>(hbuf, fc1, fc2, htmp);

  // ---- m2a + batch reduce ----
  m2a_k<<<g1(E2_), 256, 0, stream>>>(htmp, mdst, asrc, sh2, m2a_W, EL2, T4, af);
  bsum_k<<<g1(N_), 256, 0, stream>>>(af, batch, out);
}